// Round 2
// baseline (4342.196 us; speedup 1.0000x reference)
//
#include <hip/hip_runtime.h>

#define BB 2
#define CH_FEAT 128
#define HEADS 4
#define DH 64
#define INNER 256
#define NPOS 13824   // 24^3
#define MPOS 512     // 8^3
#define DSZ 24

// ---------------- map q/v projection: mqv = map_qv_w @ smap, head-split ----
__global__ __launch_bounds__(512) void k_map_qv(const float* __restrict__ smap,
                                                const float* __restrict__ w,
                                                float* __restrict__ mapq,
                                                float* __restrict__ mapv) {
  int bm = blockIdx.x;
  int b = bm >> 9, m = bm & 511;
  __shared__ float s[64];
  int t = threadIdx.x;
  if (t < 64) s[t] = smap[(size_t)(b * 64 + t) * MPOS + m];
  __syncthreads();
  const float* wr = w + t * 64;
  float acc = 0.f;
#pragma unroll
  for (int c = 0; c < 64; ++c) acc += wr[c] * s[c];
  int qv = t >> 8, c2 = t & 255, head = c2 & 3, dh = c2 >> 2;
  float* dst = qv ? mapv : mapq;
  float val = qv ? acc : acc * 0.125f;  // fold attention scale into map_q
  dst[(((size_t)b * HEADS + head) * MPOS + m) * DH + dh] = val;
}

// ---------------- depthwise 3x3x3 SAME conv (generic channel count) --------
__global__ __launch_bounds__(256) void k_dw(const float* __restrict__ in,
                                            const float* __restrict__ w,
                                            float* __restrict__ out, int C) {
  int idx = blockIdx.x * 256 + threadIdx.x;
  int n = idx % NPOS;
  int bc = idx / NPOS;
  int c = bc % C;
  int x = n % DSZ, y = (n / DSZ) % DSZ, z = n / (DSZ * DSZ);
  const float* wr = w + c * 27;
  const float* ip = in + (size_t)bc * NPOS;
  float acc = 0.f;
#pragma unroll
  for (int dz = -1; dz <= 1; ++dz) {
    int zz = z + dz;
    if (zz < 0 || zz >= DSZ) continue;
#pragma unroll
    for (int dy = -1; dy <= 1; ++dy) {
      int yy = y + dy;
      if (yy < 0 || yy >= DSZ) continue;
#pragma unroll
      for (int dx = -1; dx <= 1; ++dx) {
        int xx = x + dx;
        if (xx < 0 || xx >= DSZ) continue;
        acc += wr[(dz + 1) * 9 + (dy + 1) * 3 + (dx + 1)] *
               ip[(zz * DSZ + yy) * DSZ + xx];
      }
    }
  }
  out[idx] = acc;
}

// ---------------- pointwise qv GEMM: [512,128] x dwt -> fq/fv head-split ---
__global__ __launch_bounds__(256) void k_pw_qv(const float* __restrict__ dwt,
                                               const float* __restrict__ pw,
                                               float* __restrict__ fq,
                                               float* __restrict__ fv) {
  __shared__ __align__(16) float sA[128][68];  // dwt[k][n]
  __shared__ __align__(16) float sW[128][68];  // pw^T[k][co]
  int n0 = blockIdx.x * 64, co0 = blockIdx.y * 64, b = blockIdx.z;
  int t = threadIdx.x;
#pragma unroll
  for (int r = 0; r < 32; ++r) {
    int e = r * 256 + t;
    int k = e >> 6, n = e & 63;
    sA[k][n] = dwt[((size_t)b * CH_FEAT + k) * NPOS + n0 + n];
  }
#pragma unroll
  for (int r = 0; r < 32; ++r) {
    int e = r * 256 + t;
    int k = e & 127, co = e >> 7;
    sW[k][co] = pw[(size_t)(co0 + co) * CH_FEAT + k];
  }
  __syncthreads();
  int tx = t & 15, ty = t >> 4;
  float acc[4][4] = {};
#pragma unroll 4
  for (int k = 0; k < 128; ++k) {
    float4 a = *(const float4*)&sA[k][tx * 4];
    float4 wv = *(const float4*)&sW[k][ty * 4];
    float av[4] = {a.x, a.y, a.z, a.w};
    float wvv[4] = {wv.x, wv.y, wv.z, wv.w};
#pragma unroll
    for (int i = 0; i < 4; ++i)
#pragma unroll
      for (int j = 0; j < 4; ++j) acc[i][j] += wvv[i] * av[j];
  }
#pragma unroll
  for (int i = 0; i < 4; ++i) {
    int co = co0 + ty * 4 + i;
    int qv = co >> 8, c2 = co & 255, head = c2 & 3, dh = c2 >> 2;
    float* dst = qv ? fv : fq;
    size_t base = (((size_t)b * HEADS + head) * NPOS) * (size_t)DH + dh;
#pragma unroll
    for (int j = 0; j < 4; ++j) {
      int n = n0 + tx * 4 + j;
      dst[base + (size_t)n * DH] = acc[i][j];
    }
  }
}

// ---------------- attention row pass: 2 lanes per row, d split 32/32 -------
// lane pair (2k,2k+1) shares one feat row j; each lane owns 32 of 64 dims.
__global__ __launch_bounds__(256) void k_attn_row(const float* __restrict__ fq,
                                                  const float* __restrict__ mapq,
                                                  const float* __restrict__ mapv,
                                                  float* __restrict__ F) {
  int t = threadIdx.x;
  int lane = t & 63;
  int half = lane & 1;
  int jloc = ((t >> 6) << 5) + (lane >> 1);  // 0..127
  int j = blockIdx.x * 128 + jloc;
  int bh = blockIdx.y;
  int d0 = half << 5;

  const float4* qp = (const float4*)(fq + ((size_t)bh * NPOS + j) * DH + d0);
  float4 q[8], acc[8];
#pragma unroll
  for (int r = 0; r < 8; ++r) q[r] = qp[r];
#pragma unroll
  for (int r = 0; r < 8; ++r) acc[r] = make_float4(0.f, 0.f, 0.f, 0.f);
  float l = 0.f;

  const float* Kb = mapq + (size_t)bh * MPOS * DH + d0;
  const float* Vb = mapv + (size_t)bh * MPOS * DH + d0;
  for (int i = 0; i < MPOS; ++i) {
    const float4* kr = (const float4*)(Kb + (size_t)i * DH);
    float4 sd = make_float4(0.f, 0.f, 0.f, 0.f);
#pragma unroll
    for (int r = 0; r < 8; ++r) {
      float4 k4 = kr[r];
      sd.x += q[r].x * k4.x; sd.y += q[r].y * k4.y;
      sd.z += q[r].z * k4.z; sd.w += q[r].w * k4.w;
    }
    float s = (sd.x + sd.y) + (sd.z + sd.w);
    s += __shfl_xor(s, 1);      // combine the two d-halves
    float p = __expf(s);        // |s| << 1: no max-subtraction needed
    l += p;
    const float4* vr = (const float4*)(Vb + (size_t)i * DH);
#pragma unroll
    for (int r = 0; r < 8; ++r) {
      float4 v4 = vr[r];
      acc[r].x += p * v4.x; acc[r].y += p * v4.y;
      acc[r].z += p * v4.z; acc[r].w += p * v4.w;
    }
  }
  float rl = 1.f / l;
  int b = bh >> 2, head = bh & 3;
  float* Fb = F + (size_t)b * INNER * NPOS + j;
#pragma unroll
  for (int r = 0; r < 8; ++r) {
    float vals[4] = {acc[r].x, acc[r].y, acc[r].z, acc[r].w};
#pragma unroll
    for (int e = 0; e < 4; ++e) {
      int dglob = d0 + r * 4 + e;
      Fb[(size_t)(dglob * HEADS + head) * NPOS] = vals[e] * rl;  // merged heads
    }
  }
}

// ---------------- attention column pass: same structure over map cols ------
// partials combined via fp32 atomics into Mbuf[bh][i][65] (L2-resident, 1 MB)
__global__ __launch_bounds__(256) void k_attn_col(const float* __restrict__ fq,
                                                  const float* __restrict__ fv,
                                                  const float* __restrict__ mapq,
                                                  float* __restrict__ Mbuf,
                                                  int jlen) {
  int t = threadIdx.x;
  int lane = t & 63;
  int half = lane & 1;
  int iloc = ((t >> 6) << 5) + (lane >> 1);  // 0..127
  int i = blockIdx.x * 128 + iloc;
  int bh = blockIdx.y;
  int d0 = half << 5;

  const float4* kp = (const float4*)(mapq + ((size_t)bh * MPOS + i) * DH + d0);
  float4 k[8], acc[8];
#pragma unroll
  for (int r = 0; r < 8; ++r) k[r] = kp[r];
#pragma unroll
  for (int r = 0; r < 8; ++r) acc[r] = make_float4(0.f, 0.f, 0.f, 0.f);
  float l = 0.f;

  int j0 = blockIdx.z * jlen;
  const float* Qb = fq + (size_t)bh * NPOS * DH + d0;
  const float* Vb = fv + (size_t)bh * NPOS * DH + d0;
  for (int j = j0; j < j0 + jlen; ++j) {
    const float4* qr = (const float4*)(Qb + (size_t)j * DH);
    float4 sd = make_float4(0.f, 0.f, 0.f, 0.f);
#pragma unroll
    for (int r = 0; r < 8; ++r) {
      float4 q4 = qr[r];
      sd.x += k[r].x * q4.x; sd.y += k[r].y * q4.y;
      sd.z += k[r].z * q4.z; sd.w += k[r].w * q4.w;
    }
    float s = (sd.x + sd.y) + (sd.z + sd.w);
    s += __shfl_xor(s, 1);
    float p = __expf(s);
    l += p;
    const float4* vr = (const float4*)(Vb + (size_t)j * DH);
#pragma unroll
    for (int r = 0; r < 8; ++r) {
      float4 v4 = vr[r];
      acc[r].x += p * v4.x; acc[r].y += p * v4.y;
      acc[r].z += p * v4.z; acc[r].w += p * v4.w;
    }
  }
  float* g = Mbuf + ((size_t)bh * MPOS + i) * 65 + d0;
#pragma unroll
  for (int r = 0; r < 8; ++r) {
    float vals[4] = {acc[r].x, acc[r].y, acc[r].z, acc[r].w};
#pragma unroll
    for (int e = 0; e < 4; ++e) atomicAdd(&g[r * 4 + e], vals[e]);
  }
  if (!half) atomicAdd(Mbuf + ((size_t)bh * MPOS + i) * 65 + 64, l);
}

// ---------------- normalize cols + map_out projection ----------------------
__global__ __launch_bounds__(256) void k_map_out(const float* __restrict__ Mbuf,
                                                 const float* __restrict__ mow,
                                                 float* __restrict__ out2) {
  int m = blockIdx.x;
  int b = blockIdx.y;
  int t = threadIdx.x;
  __shared__ float sMA[256];
  __shared__ float sL[4];
  if (t < 4) sL[t] = 1.f / Mbuf[((size_t)(b * HEADS + t) * MPOS + m) * 65 + 64];
  __syncthreads();
  {
    int head = t & 3, dh = t >> 2;  // merged channel c = dh*4+head = t
    sMA[t] = Mbuf[((size_t)(b * HEADS + head) * MPOS + m) * 65 + dh] * sL[head];
  }
  __syncthreads();
  if (t < 64) {
    const float* wr = mow + t * 256;
    float acc = 0.f;
#pragma unroll 4
    for (int c = 0; c < 256; ++c) acc += wr[c] * sMA[c];
    out2[((size_t)b * 64 + t) * MPOS + m] = acc;
  }
}

// ---------------- pointwise out GEMM: [128,256] x dwo -> out1 --------------
__global__ __launch_bounds__(256) void k_pw_out(const float* __restrict__ dwo,
                                                const float* __restrict__ pw,
                                                float* __restrict__ out1) {
  __shared__ __align__(16) float sA[128][68];
  __shared__ __align__(16) float sW[128][68];
  int n0 = blockIdx.x * 64, co0 = blockIdx.y * 64, b = blockIdx.z;
  int t = threadIdx.x;
  int tx = t & 15, ty = t >> 4;
  float acc[4][4] = {};
  for (int kk = 0; kk < 2; ++kk) {
    __syncthreads();
#pragma unroll
    for (int r = 0; r < 32; ++r) {
      int e = r * 256 + t;
      int k = e >> 6, n = e & 63;
      sA[k][n] = dwo[((size_t)b * INNER + kk * 128 + k) * NPOS + n0 + n];
    }
#pragma unroll
    for (int r = 0; r < 32; ++r) {
      int e = r * 256 + t;
      int k = e & 127, co = e >> 7;
      sW[k][co] = pw[(size_t)(co0 + co) * INNER + kk * 128 + k];
    }
    __syncthreads();
#pragma unroll 4
    for (int k = 0; k < 128; ++k) {
      float4 a = *(const float4*)&sA[k][tx * 4];
      float4 wv = *(const float4*)&sW[k][ty * 4];
      float av[4] = {a.x, a.y, a.z, a.w};
      float wvv[4] = {wv.x, wv.y, wv.z, wv.w};
#pragma unroll
      for (int i = 0; i < 4; ++i)
#pragma unroll
        for (int j = 0; j < 4; ++j) acc[i][j] += wvv[i] * av[j];
    }
  }
#pragma unroll
  for (int i = 0; i < 4; ++i) {
    int co = co0 + ty * 4 + i;
#pragma unroll
    for (int j = 0; j < 4; ++j) {
      int n = n0 + tx * 4 + j;
      out1[((size_t)b * 128 + co) * NPOS + n] = acc[i][j];
    }
  }
}

extern "C" void kernel_launch(void* const* d_in, const int* in_sizes, int n_in,
                              void* d_out, int out_size, void* d_ws, size_t ws_size,
                              hipStream_t stream) {
  const float* feat = (const float*)d_in[0];
  const float* smap = (const float*)d_in[1];
  const float* fqv_dw = (const float*)d_in[2];
  const float* fqv_pw = (const float*)d_in[3];
  const float* fout_dw = (const float*)d_in[4];
  const float* fout_pw = (const float*)d_in[5];
  const float* mqv_w = (const float*)d_in[6];
  const float* mout_w = (const float*)d_in[7];

  float* out = (float*)d_out;
  float* out1 = out;                              // [2,128,24,24,24]
  float* out2 = out + (size_t)BB * 128 * NPOS;    // [2,64,8,8,8]

  float* ws = (float*)d_ws;
  const size_t QV = (size_t)BB * HEADS * NPOS * DH;    // 7,077,888
  const size_t MQV = (size_t)BB * HEADS * MPOS * DH;   // 262,144
  float* fq = ws;
  float* fv = fq + QV;
  float* F = fv + QV;
  float* mapq = F + QV;
  float* mapv = mapq + MQV;
  float* Mbuf = mapv + MQV;                       // [8][512][65] col partials

  // dwt lives in d_out (fits in the out1 region); dwo reuses fq after col pass
  float* dwt = out1;
  float* dwo = fq;

  const int JCH = 32;
  const int JLEN = NPOS / JCH;  // 432

  hipMemsetAsync(Mbuf, 0, (size_t)BB * HEADS * MPOS * 65 * 4, stream);
  k_map_qv<<<dim3(BB * MPOS), dim3(512), 0, stream>>>(smap, mqv_w, mapq, mapv);
  k_dw<<<dim3(BB * CH_FEAT * NPOS / 256), dim3(256), 0, stream>>>(feat, fqv_dw, dwt, CH_FEAT);
  k_pw_qv<<<dim3(NPOS / 64, 8, BB), dim3(256), 0, stream>>>(dwt, fqv_pw, fq, fv);
  k_attn_row<<<dim3(NPOS / 128, BB * HEADS), dim3(256), 0, stream>>>(fq, mapq, mapv, F);
  k_attn_col<<<dim3(MPOS / 128, BB * HEADS, JCH), dim3(256), 0, stream>>>(fq, fv, mapq, Mbuf, JLEN);
  k_map_out<<<dim3(MPOS, BB), dim3(256), 0, stream>>>(Mbuf, mout_w, out2);
  k_dw<<<dim3(BB * INNER * NPOS / 256), dim3(256), 0, stream>>>(F, fout_dw, dwo, INNER);
  k_pw_out<<<dim3(NPOS / 64, 2, BB), dim3(256), 0, stream>>>(dwo, fout_pw, out1);
}

// Round 3
// 1660.371 us; speedup vs baseline: 2.6152x; 2.6152x over previous
//
#include <hip/hip_runtime.h>

#define BB 2
#define CH_FEAT 128
#define HEADS 4
#define DH 64
#define INNER 256
#define NPOS 13824   // 24^3
#define MPOS 512     // 8^3
#define DSZ 24

// ---------------- map q/v projection: mqv = map_qv_w @ smap, head-split ----
__global__ __launch_bounds__(512) void k_map_qv(const float* __restrict__ smap,
                                                const float* __restrict__ w,
                                                float* __restrict__ mapq,
                                                float* __restrict__ mapv) {
  int bm = blockIdx.x;
  int b = bm >> 9, m = bm & 511;
  __shared__ float s[64];
  int t = threadIdx.x;
  if (t < 64) s[t] = smap[(size_t)(b * 64 + t) * MPOS + m];
  __syncthreads();
  const float* wr = w + t * 64;
  float acc = 0.f;
#pragma unroll
  for (int c = 0; c < 64; ++c) acc += wr[c] * s[c];
  int qv = t >> 8, c2 = t & 255, head = c2 & 3, dh = c2 >> 2;
  float* dst = qv ? mapv : mapq;
  float val = qv ? acc : acc * 0.125f;  // fold attention scale into map_q
  dst[(((size_t)b * HEADS + head) * MPOS + m) * DH + dh] = val;
}

// ---------------- depthwise 3x3x3 SAME conv (generic channel count) --------
__global__ __launch_bounds__(256) void k_dw(const float* __restrict__ in,
                                            const float* __restrict__ w,
                                            float* __restrict__ out, int C) {
  int idx = blockIdx.x * 256 + threadIdx.x;
  int n = idx % NPOS;
  int bc = idx / NPOS;
  int c = bc % C;
  int x = n % DSZ, y = (n / DSZ) % DSZ, z = n / (DSZ * DSZ);
  const float* wr = w + c * 27;
  const float* ip = in + (size_t)bc * NPOS;
  float acc = 0.f;
#pragma unroll
  for (int dz = -1; dz <= 1; ++dz) {
    int zz = z + dz;
    if (zz < 0 || zz >= DSZ) continue;
#pragma unroll
    for (int dy = -1; dy <= 1; ++dy) {
      int yy = y + dy;
      if (yy < 0 || yy >= DSZ) continue;
#pragma unroll
      for (int dx = -1; dx <= 1; ++dx) {
        int xx = x + dx;
        if (xx < 0 || xx >= DSZ) continue;
        acc += wr[(dz + 1) * 9 + (dy + 1) * 3 + (dx + 1)] *
               ip[(zz * DSZ + yy) * DSZ + xx];
      }
    }
  }
  out[idx] = acc;
}

// ---------------- pointwise qv GEMM: [512,128] x dwt -> fq/fv head-split ---
__global__ __launch_bounds__(256) void k_pw_qv(const float* __restrict__ dwt,
                                               const float* __restrict__ pw,
                                               float* __restrict__ fq,
                                               float* __restrict__ fv) {
  __shared__ __align__(16) float sA[128][68];  // dwt[k][n]
  __shared__ __align__(16) float sW[128][68];  // pw^T[k][co]
  int n0 = blockIdx.x * 64, co0 = blockIdx.y * 64, b = blockIdx.z;
  int t = threadIdx.x;
#pragma unroll
  for (int r = 0; r < 32; ++r) {
    int e = r * 256 + t;
    int k = e >> 6, n = e & 63;
    sA[k][n] = dwt[((size_t)b * CH_FEAT + k) * NPOS + n0 + n];
  }
#pragma unroll
  for (int r = 0; r < 32; ++r) {
    int e = r * 256 + t;
    int k = e & 127, co = e >> 7;
    sW[k][co] = pw[(size_t)(co0 + co) * CH_FEAT + k];
  }
  __syncthreads();
  int tx = t & 15, ty = t >> 4;
  float acc[4][4] = {};
#pragma unroll 4
  for (int k = 0; k < 128; ++k) {
    float4 a = *(const float4*)&sA[k][tx * 4];
    float4 wv = *(const float4*)&sW[k][ty * 4];
    float av[4] = {a.x, a.y, a.z, a.w};
    float wvv[4] = {wv.x, wv.y, wv.z, wv.w};
#pragma unroll
    for (int i = 0; i < 4; ++i)
#pragma unroll
      for (int j = 0; j < 4; ++j) acc[i][j] += wvv[i] * av[j];
  }
#pragma unroll
  for (int i = 0; i < 4; ++i) {
    int co = co0 + ty * 4 + i;
    int qv = co >> 8, c2 = co & 255, head = c2 & 3, dh = c2 >> 2;
    float* dst = qv ? fv : fq;
    size_t base = (((size_t)b * HEADS + head) * NPOS) * (size_t)DH + dh;
#pragma unroll
    for (int j = 0; j < 4; ++j) {
      int n = n0 + tx * 4 + j;
      dst[base + (size_t)n * DH] = acc[i][j];
    }
  }
}

// ---------------- attention row pass: 1 thread per feat row ----------------
// K/V row addresses are wave-uniform -> scalar loads (the round-1 win).
// msplit>1: each block covers an M-chunk, partials to Gacc/Gl (coalesced).
__global__ __launch_bounds__(64) void k_attn_row(const float* __restrict__ fq,
                                                 const float* __restrict__ mapq,
                                                 const float* __restrict__ mapv,
                                                 float* __restrict__ F,
                                                 float* __restrict__ Gacc,
                                                 float* __restrict__ Gl,
                                                 int msplit) {
  int j = blockIdx.x * 64 + threadIdx.x;
  int bh = blockIdx.y;
  int chunk = blockIdx.z;
  int mlen = MPOS / msplit;
  int i0 = chunk * mlen;

  const float* qp = fq + ((size_t)bh * NPOS + j) * DH;
  float q[64];
#pragma unroll
  for (int d = 0; d < 64; d += 4) {
    float4 v = *(const float4*)(qp + d);
    q[d] = v.x; q[d + 1] = v.y; q[d + 2] = v.z; q[d + 3] = v.w;
  }
  float acc[64];
#pragma unroll
  for (int d = 0; d < 64; ++d) acc[d] = 0.f;
  float l = 0.f;

  const float* Kb = mapq + (size_t)bh * MPOS * DH;
  const float* Vb = mapv + (size_t)bh * MPOS * DH;
  for (int i = i0; i < i0 + mlen; ++i) {
    const float* kr = Kb + (size_t)i * DH;  // uniform -> scalar loads
    float s0 = 0.f, s1 = 0.f, s2 = 0.f, s3 = 0.f;  // 4-way dot partials
#pragma unroll
    for (int d = 0; d < 64; d += 4) {
      s0 += q[d] * kr[d];
      s1 += q[d + 1] * kr[d + 1];
      s2 += q[d + 2] * kr[d + 2];
      s3 += q[d + 3] * kr[d + 3];
    }
    float p = __expf((s0 + s1) + (s2 + s3));  // |s| << 1: no max needed
    l += p;
    const float* vr = Vb + (size_t)i * DH;  // uniform -> scalar loads
#pragma unroll
    for (int d = 0; d < 64; ++d) acc[d] += p * vr[d];
  }

  if (msplit == 1) {
    float rl = 1.f / l;
    int b = bh >> 2, head = bh & 3;
    float* Fb = F + (size_t)b * INNER * NPOS + j;
#pragma unroll
    for (int d = 0; d < 64; ++d)
      Fb[(size_t)(d * HEADS + head) * NPOS] = acc[d] * rl;  // merged heads
  } else {
    float* g = Gacc + (((size_t)(chunk * 8 + bh)) * 64) * NPOS + j;
#pragma unroll
    for (int d = 0; d < 64; ++d) g[(size_t)d * NPOS] = acc[d];
    Gl[(size_t)(chunk * 8 + bh) * NPOS + j] = l;
  }
}

// ---------------- combine row partials -> normalized F ---------------------
__global__ __launch_bounds__(256) void k_row_combine(const float* __restrict__ Gacc,
                                                     const float* __restrict__ Gl,
                                                     float* __restrict__ F,
                                                     int msplit) {
  int j = blockIdx.x * 256 + threadIdx.x;
  int bh = blockIdx.y;
  float l = 0.f;
  for (int c = 0; c < msplit; ++c) l += Gl[(size_t)(c * 8 + bh) * NPOS + j];
  float rl = 1.f / l;
  int b = bh >> 2, head = bh & 3;
  float* Fb = F + (size_t)b * INNER * NPOS + j;
  for (int d = 0; d < 64; ++d) {
    float a = 0.f;
    for (int c = 0; c < msplit; ++c)
      a += Gacc[(((size_t)(c * 8 + bh)) * 64 + d) * NPOS + j];
    Fb[(size_t)(d * HEADS + head) * NPOS] = a * rl;
  }
}

// ---------------- attention column pass: 1 thread per map col, j-chunked ---
__global__ __launch_bounds__(64) void k_attn_col(const float* __restrict__ fq,
                                                 const float* __restrict__ fv,
                                                 const float* __restrict__ mapq,
                                                 float* __restrict__ Ga,
                                                 float* __restrict__ Gli,
                                                 int jch, int jlen) {
  int i = blockIdx.x * 64 + threadIdx.x;  // 0..511
  int bh = blockIdx.y;
  int chunk = blockIdx.z;
  int j0 = chunk * jlen;
  int j1 = j0 + jlen;
  if (j1 > NPOS) j1 = NPOS;

  const float* kp = mapq + ((size_t)bh * MPOS + i) * DH;
  float k[64];
#pragma unroll
  for (int d = 0; d < 64; d += 4) {
    float4 v = *(const float4*)(kp + d);
    k[d] = v.x; k[d + 1] = v.y; k[d + 2] = v.z; k[d + 3] = v.w;
  }
  float acc[64];
#pragma unroll
  for (int d = 0; d < 64; ++d) acc[d] = 0.f;
  float l = 0.f;

  const float* Qb = fq + (size_t)bh * NPOS * DH;
  const float* Vb = fv + (size_t)bh * NPOS * DH;
  for (int j = j0; j < j1; ++j) {
    const float* qp = Qb + (size_t)j * DH;  // uniform -> scalar loads
    float s0 = 0.f, s1 = 0.f, s2 = 0.f, s3 = 0.f;
#pragma unroll
    for (int d = 0; d < 64; d += 4) {
      s0 += k[d] * qp[d];
      s1 += k[d + 1] * qp[d + 1];
      s2 += k[d + 2] * qp[d + 2];
      s3 += k[d + 3] * qp[d + 3];
    }
    float p = __expf((s0 + s1) + (s2 + s3));
    l += p;
    const float* vp = Vb + (size_t)j * DH;  // uniform -> scalar loads
#pragma unroll
    for (int d = 0; d < 64; ++d) acc[d] += p * vp[d];
  }
  float* g = Ga + (((size_t)(bh * jch + chunk)) * 64) * MPOS + i;
#pragma unroll
  for (int d = 0; d < 64; ++d) g[(size_t)d * MPOS] = acc[d];  // coalesced
  Gli[(size_t)(bh * jch + chunk) * MPOS + i] = l;
}

// ---------------- combine col partials + map_out projection ----------------
__global__ __launch_bounds__(256) void k_map_out(const float* __restrict__ Ga,
                                                 const float* __restrict__ Gli,
                                                 const float* __restrict__ mow,
                                                 float* __restrict__ out2,
                                                 int jch) {
  int m = blockIdx.x;
  int b = blockIdx.y;
  int t = threadIdx.x;
  __shared__ float sMA[256];
  __shared__ float sL[4];
  if (t < 4) {
    float l = 0.f;
    for (int ch = 0; ch < jch; ++ch)
      l += Gli[(size_t)((b * 4 + t) * jch + ch) * MPOS + m];
    sL[t] = 1.f / l;
  }
  __syncthreads();
  {
    int head = t & 3, dh = t >> 2;  // merged channel c = dh*4+head = t
    int bh = b * 4 + head;
    float a = 0.f;
    for (int ch = 0; ch < jch; ++ch)
      a += Ga[(((size_t)(bh * jch + ch)) * 64 + dh) * MPOS + m];
    sMA[t] = a * sL[head];
  }
  __syncthreads();
  if (t < 64) {
    const float* wr = mow + t * 256;
    float acc = 0.f;
#pragma unroll 4
    for (int c = 0; c < 256; ++c) acc += wr[c] * sMA[c];
    out2[((size_t)b * 64 + t) * MPOS + m] = acc;
  }
}

// ---------------- pointwise out GEMM: [128,256] x dwo -> out1 --------------
__global__ __launch_bounds__(256) void k_pw_out(const float* __restrict__ dwo,
                                                const float* __restrict__ pw,
                                                float* __restrict__ out1) {
  __shared__ __align__(16) float sA[128][68];
  __shared__ __align__(16) float sW[128][68];
  int n0 = blockIdx.x * 64, co0 = blockIdx.y * 64, b = blockIdx.z;
  int t = threadIdx.x;
  int tx = t & 15, ty = t >> 4;
  float acc[4][4] = {};
  for (int kk = 0; kk < 2; ++kk) {
    __syncthreads();
#pragma unroll
    for (int r = 0; r < 32; ++r) {
      int e = r * 256 + t;
      int k = e >> 6, n = e & 63;
      sA[k][n] = dwo[((size_t)b * INNER + kk * 128 + k) * NPOS + n0 + n];
    }
#pragma unroll
    for (int r = 0; r < 32; ++r) {
      int e = r * 256 + t;
      int k = e & 127, co = e >> 7;
      sW[k][co] = pw[(size_t)(co0 + co) * INNER + kk * 128 + k];
    }
    __syncthreads();
#pragma unroll 4
    for (int k = 0; k < 128; ++k) {
      float4 a = *(const float4*)&sA[k][tx * 4];
      float4 wv = *(const float4*)&sW[k][ty * 4];
      float av[4] = {a.x, a.y, a.z, a.w};
      float wvv[4] = {wv.x, wv.y, wv.z, wv.w};
#pragma unroll
      for (int i = 0; i < 4; ++i)
#pragma unroll
        for (int j = 0; j < 4; ++j) acc[i][j] += wvv[i] * av[j];
    }
  }
#pragma unroll
  for (int i = 0; i < 4; ++i) {
    int co = co0 + ty * 4 + i;
#pragma unroll
    for (int j = 0; j < 4; ++j) {
      int n = n0 + tx * 4 + j;
      out1[((size_t)b * 128 + co) * NPOS + n] = acc[i][j];
    }
  }
}

extern "C" void kernel_launch(void* const* d_in, const int* in_sizes, int n_in,
                              void* d_out, int out_size, void* d_ws, size_t ws_size,
                              hipStream_t stream) {
  const float* feat = (const float*)d_in[0];
  const float* smap = (const float*)d_in[1];
  const float* fqv_dw = (const float*)d_in[2];
  const float* fqv_pw = (const float*)d_in[3];
  const float* fout_dw = (const float*)d_in[4];
  const float* fout_pw = (const float*)d_in[5];
  const float* mqv_w = (const float*)d_in[6];
  const float* mout_w = (const float*)d_in[7];

  float* out = (float*)d_out;
  float* out1 = out;                              // [2,128,24,24,24]
  float* out2 = out + (size_t)BB * 128 * NPOS;    // [2,64,8,8,8]

  float* ws = (float*)d_ws;
  const size_t QV = (size_t)BB * HEADS * NPOS * DH;    // 7,077,888
  const size_t MQV = (size_t)BB * HEADS * MPOS * DH;   // 262,144
  float* fq = ws;
  float* fv = fq + QV;
  float* F = fv + QV;
  float* mapq = F + QV;
  float* mapv = mapq + MQV;
  float* tail = mapv + MQV;
  size_t base_floats = (size_t)(tail - ws);            // 21,757,952

  // ws-adaptive parallelism split (round-1 ws floor = base + 1 col chunk)
  long avail = (long)(ws_size / 4) - (long)base_floats;
  const long ROWCH = 8L * (NPOS * 64 + NPOS);          // 7,188,480 floats/chunk
  const long COLCH = 8L * (MPOS * 64 + MPOS);          // 266,240 floats/chunk
  int msplit = 1;
  if (avail >= 4 * ROWCH + 8 * COLCH) msplit = 4;
  else if (avail >= 2 * ROWCH + 4 * COLCH) msplit = 2;
  long after_row = avail - (msplit > 1 ? msplit * ROWCH : 0);
  int jch = (int)(after_row / COLCH);
  if (jch < 1) jch = 1;
  if (jch > 32) jch = 32;
  int jlen = (NPOS + jch - 1) / jch;

  float* Gl = tail;                                    // [msplit*8][NPOS]
  float* Gacc = Gl + (msplit > 1 ? (size_t)msplit * 8 * NPOS : 0);
  float* Gcl = Gacc + (msplit > 1 ? (size_t)msplit * 8 * 64 * NPOS : 0);
  float* Gca = Gcl + (size_t)jch * 8 * MPOS;

  // dwt lives in d_out (out1 region); dwo reuses fq after the col pass
  float* dwt = out1;
  float* dwo = fq;

  k_map_qv<<<dim3(BB * MPOS), dim3(512), 0, stream>>>(smap, mqv_w, mapq, mapv);
  k_dw<<<dim3(BB * CH_FEAT * NPOS / 256), dim3(256), 0, stream>>>(feat, fqv_dw, dwt, CH_FEAT);
  k_pw_qv<<<dim3(NPOS / 64, 8, BB), dim3(256), 0, stream>>>(dwt, fqv_pw, fq, fv);
  k_attn_row<<<dim3(NPOS / 64, BB * HEADS, msplit), dim3(64), 0, stream>>>(
      fq, mapq, mapv, F, Gacc, Gl, msplit);
  if (msplit > 1)
    k_row_combine<<<dim3(NPOS / 256, BB * HEADS), dim3(256), 0, stream>>>(Gacc, Gl, F, msplit);
  k_attn_col<<<dim3(MPOS / 64, BB * HEADS, jch), dim3(64), 0, stream>>>(
      fq, fv, mapq, Gca, Gcl, jch, jlen);
  k_map_out<<<dim3(MPOS, BB), dim3(256), 0, stream>>>(Gca, Gcl, mout_w, out2, jch);
  k_dw<<<dim3(BB * INNER * NPOS / 256), dim3(256), 0, stream>>>(F, fout_dw, dwo, INNER);
  k_pw_out<<<dim3(NPOS / 64, 2, BB), dim3(256), 0, stream>>>(dwo, fout_pw, out1);
}

// Round 4
// 498.865 us; speedup vs baseline: 8.7042x; 3.3283x over previous
//
#include <hip/hip_runtime.h>

#define BB 2
#define CH_FEAT 128
#define HEADS 4
#define DH 64
#define INNER 256
#define NPOS 13824   // 24^3
#define MPOS 512     // 8^3
#define DSZ 24
#define JSPLIT 8     // col-pass j chunks
#define JCHUNK (NPOS / JSPLIT)  // 1728

typedef __attribute__((ext_vector_type(8))) short bf16x8;
typedef __attribute__((ext_vector_type(4))) float f32x4;

__device__ inline unsigned short bf16_rn(float x) {
  unsigned u = __builtin_bit_cast(unsigned, x);
  u += 0x7FFF + ((u >> 16) & 1);
  return (unsigned short)(u >> 16);
}
__device__ inline unsigned pk_bf16(float a, float b) {
  return (unsigned)bf16_rn(a) | ((unsigned)bf16_rn(b) << 16);
}

// ---------------- map q/v projection -> bf16 mapq [bh][m][d], mapv^T [bh][d][m]
__global__ __launch_bounds__(512) void k_map_qv(const float* __restrict__ smap,
                                                const float* __restrict__ w,
                                                unsigned short* __restrict__ mapqb,
                                                unsigned short* __restrict__ mapvTb) {
  int bm = blockIdx.x;
  int b = bm >> 9, m = bm & 511;
  __shared__ float s[64];
  int t = threadIdx.x;
  if (t < 64) s[t] = smap[(size_t)(b * 64 + t) * MPOS + m];
  __syncthreads();
  const float* wr = w + t * 64;
  float acc = 0.f;
#pragma unroll
  for (int c = 0; c < 64; ++c) acc += wr[c] * s[c];
  int qv = t >> 8, c2 = t & 255, head = c2 & 3, dh = c2 >> 2;
  int bh = b * HEADS + head;
  if (qv == 0)
    mapqb[((size_t)bh * MPOS + m) * 64 + dh] = bf16_rn(acc * 0.125f);  // fold scale
  else
    mapvTb[((size_t)bh * 64 + dh) * MPOS + m] = bf16_rn(acc);
}

// ---------------- depthwise 3x3x3 SAME conv; optional head-merge channel remap
__global__ __launch_bounds__(256) void k_dw(const float* __restrict__ in,
                                            const float* __restrict__ w,
                                            float* __restrict__ out, int C, int remap) {
  int idx = blockIdx.x * 256 + threadIdx.x;
  int n = idx % NPOS;
  int bc = idx / NPOS;
  int c = bc % C, b = bc / C;
  int cm = remap ? ((c & 63) * 4 + (c >> 6)) : c;  // storage head*64+d -> merged d*4+head
  int x = n % DSZ, y = (n / DSZ) % DSZ, z = n / (DSZ * DSZ);
  const float* wr = w + cm * 27;
  const float* ip = in + (size_t)bc * NPOS;
  float acc = 0.f;
#pragma unroll
  for (int dz = -1; dz <= 1; ++dz) {
    int zz = z + dz;
    if (zz < 0 || zz >= DSZ) continue;
#pragma unroll
    for (int dy = -1; dy <= 1; ++dy) {
      int yy = y + dy;
      if (yy < 0 || yy >= DSZ) continue;
#pragma unroll
      for (int dx = -1; dx <= 1; ++dx) {
        int xx = x + dx;
        if (xx < 0 || xx >= DSZ) continue;
        acc += wr[(dz + 1) * 9 + (dy + 1) * 3 + (dx + 1)] *
               ip[(zz * DSZ + yy) * DSZ + xx];
      }
    }
  }
  out[((size_t)b * C + cm) * NPOS + n] = acc;
}

// ---------------- pointwise qv GEMM -> fq bf16 [bh][j][d], fv^T bf16 [bh][d][j]
__global__ __launch_bounds__(256) void k_pw_qv(const float* __restrict__ dwt,
                                               const float* __restrict__ pw,
                                               unsigned short* __restrict__ fqb,
                                               unsigned short* __restrict__ fvTb) {
  __shared__ __align__(16) float sA[128][68];  // dwt[k][n]
  __shared__ __align__(16) float sW[128][68];  // pw^T[k][co]
  int n0 = blockIdx.x * 64, co0 = blockIdx.y * 64, b = blockIdx.z;
  int t = threadIdx.x;
#pragma unroll
  for (int r = 0; r < 32; ++r) {
    int e = r * 256 + t;
    int k = e >> 6, n = e & 63;
    sA[k][n] = dwt[((size_t)b * CH_FEAT + k) * NPOS + n0 + n];
  }
#pragma unroll
  for (int r = 0; r < 32; ++r) {
    int e = r * 256 + t;
    int k = e & 127, co = e >> 7;
    sW[k][co] = pw[(size_t)(co0 + co) * CH_FEAT + k];
  }
  __syncthreads();
  int tx = t & 15, ty = t >> 4;
  float acc[4][4] = {};
#pragma unroll 4
  for (int k = 0; k < 128; ++k) {
    float4 a = *(const float4*)&sA[k][tx * 4];
    float4 wv = *(const float4*)&sW[k][ty * 4];
    float av[4] = {a.x, a.y, a.z, a.w};
    float wvv[4] = {wv.x, wv.y, wv.z, wv.w};
#pragma unroll
    for (int i = 0; i < 4; ++i)
#pragma unroll
      for (int j = 0; j < 4; ++j) acc[i][j] += wvv[i] * av[j];
  }
#pragma unroll
  for (int i = 0; i < 4; ++i) {
    int co = co0 + ty * 4 + i;
    int qv = co >> 8, c2 = co & 255, head = c2 & 3, dh = c2 >> 2;
    int bh = b * HEADS + head;
    int n = n0 + tx * 4;
    if (qv == 0) {
      unsigned short* dst = fqb + ((size_t)bh * NPOS + n) * 64 + dh;
#pragma unroll
      for (int j = 0; j < 4; ++j) dst[(size_t)j * 64] = bf16_rn(acc[i][j]);
    } else {
      uint2 wv2;
      wv2.x = pk_bf16(acc[i][0], acc[i][1]);
      wv2.y = pk_bf16(acc[i][2], acc[i][3]);
      *(uint2*)(fvTb + ((size_t)bh * 64 + dh) * NPOS + n) = wv2;
    }
  }
}

// ---------------- MFMA attention row pass: softmax over M, P @ map_v -------
// wave owns 16 feat rows; S^T = mfma(A=mapq, B=fq); P via LDS; PV = mfma(P, mapv^T)
__global__ __launch_bounds__(256) void k_attn_row(const unsigned short* __restrict__ fqb,
                                                  const unsigned short* __restrict__ mapqb,
                                                  const unsigned short* __restrict__ mapvTb,
                                                  float* __restrict__ F) {
  __shared__ unsigned sP[4][16][36];  // per-wave P tile [16 j][72 bf16 padded]
  __shared__ float sL[4][16];
  int t = threadIdx.x, wave = t >> 6, lane = t & 63, g = lane >> 4, c = lane & 15;
  int bh = blockIdx.y;
  int j0 = blockIdx.x * 64 + wave * 16;
  const unsigned short* fqp = fqb + ((size_t)bh * NPOS + j0 + c) * 64 + 8 * g;
  const unsigned short* Kb = mapqb + (size_t)bh * MPOS * 64;
  const unsigned short* VT = mapvTb + (size_t)bh * 64 * MPOS;
  bf16x8 bq0 = *(const bf16x8*)(fqp);
  bf16x8 bq1 = *(const bf16x8*)(fqp + 32);
  f32x4 o[4];
#pragma unroll
  for (int dt = 0; dt < 4; ++dt) o[dt] = (f32x4){0.f, 0.f, 0.f, 0.f};
  float ls = 0.f;
  for (int ic = 0; ic < 8; ++ic) {  // i-chunks of 64 over MPOS
    int ibase = ic * 64;
#pragma unroll
    for (int ti = 0; ti < 4; ++ti) {
      const unsigned short* kp = Kb + (size_t)(ibase + ti * 16 + c) * 64 + 8 * g;
      bf16x8 a0 = *(const bf16x8*)(kp);
      bf16x8 a1 = *(const bf16x8*)(kp + 32);
      f32x4 s = {0.f, 0.f, 0.f, 0.f};
      s = __builtin_amdgcn_mfma_f32_16x16x32_bf16(a0, bq0, s, 0, 0, 0);
      s = __builtin_amdgcn_mfma_f32_16x16x32_bf16(a1, bq1, s, 0, 0, 0);
      // C-frag: S^T[i=ibase+ti*16+4g+r][j=j0+c]; |s|<<1 -> exp w/o max
      float p0 = __expf(s[0]), p1 = __expf(s[1]), p2 = __expf(s[2]), p3 = __expf(s[3]);
      ls += (p0 + p1) + (p2 + p3);
      sP[wave][c][ti * 8 + 2 * g] = pk_bf16(p0, p1);
      sP[wave][c][ti * 8 + 2 * g + 1] = pk_bf16(p2, p3);
    }
#pragma unroll
    for (int ks = 0; ks < 2; ++ks) {
      bf16x8 ap = *(const bf16x8*)&sP[wave][c][ks * 16 + 4 * g];
#pragma unroll
      for (int dt = 0; dt < 4; ++dt) {
        bf16x8 bv = *(const bf16x8*)(VT + (size_t)(dt * 16 + c) * MPOS + ibase + ks * 32 + 8 * g);
        o[dt] = __builtin_amdgcn_mfma_f32_16x16x32_bf16(ap, bv, o[dt], 0, 0, 0);
      }
    }
  }
  ls += __shfl_xor(ls, 16);
  ls += __shfl_xor(ls, 32);
  if (g == 0) sL[wave][c] = 1.f / ls;
  float rl0 = sL[wave][4 * g + 0], rl1 = sL[wave][4 * g + 1];
  float rl2 = sL[wave][4 * g + 2], rl3 = sL[wave][4 * g + 3];
  int b = bh >> 2, head = bh & 3;
#pragma unroll
  for (int dt = 0; dt < 4; ++dt) {
    // D: out[j=j0+4g+r][d=dt*16+c]; F storage channel = head*64+d
    float4 v = make_float4(o[dt][0] * rl0, o[dt][1] * rl1, o[dt][2] * rl2, o[dt][3] * rl3);
    *(float4*)(F + ((size_t)b * INNER + head * 64 + dt * 16 + c) * NPOS + j0 + 4 * g) = v;
  }
}

// ---------------- MFMA attention col pass: j-chunked partials ---------------
__global__ __launch_bounds__(256) void k_attn_col(const unsigned short* __restrict__ fqb,
                                                  const unsigned short* __restrict__ fvTb,
                                                  const unsigned short* __restrict__ mapqb,
                                                  float* __restrict__ Gc,
                                                  float* __restrict__ Gl) {
  __shared__ unsigned sPT[4][16][36];  // per-wave P^T tile [16 i][72 bf16 padded]
  int t = threadIdx.x, wave = t >> 6, lane = t & 63, g = lane >> 4, c = lane & 15;
  int bh = blockIdx.y, chunk = blockIdx.z;
  int iw0 = blockIdx.x * 64 + wave * 16;
  const unsigned short* fqB = fqb + (size_t)bh * NPOS * 64;
  const unsigned short* VT = fvTb + (size_t)bh * 64 * NPOS;
  const unsigned short* kp = mapqb + ((size_t)bh * MPOS + iw0 + c) * 64 + 8 * g;
  bf16x8 bm0 = *(const bf16x8*)(kp);
  bf16x8 bm1 = *(const bf16x8*)(kp + 32);
  f32x4 o[4];
#pragma unroll
  for (int dt = 0; dt < 4; ++dt) o[dt] = (f32x4){0.f, 0.f, 0.f, 0.f};
  float lc = 0.f;
  int jbase = chunk * JCHUNK;
  for (int jc = 0; jc < JCHUNK / 64; ++jc) {  // 27 sub-chunks
    int j0 = jbase + jc * 64;
#pragma unroll
    for (int tj = 0; tj < 4; ++tj) {
      const unsigned short* qp = fqB + (size_t)(j0 + tj * 16 + c) * 64 + 8 * g;
      bf16x8 a0 = *(const bf16x8*)(qp);
      bf16x8 a1 = *(const bf16x8*)(qp + 32);
      f32x4 s = {0.f, 0.f, 0.f, 0.f};
      s = __builtin_amdgcn_mfma_f32_16x16x32_bf16(a0, bm0, s, 0, 0, 0);
      s = __builtin_amdgcn_mfma_f32_16x16x32_bf16(a1, bm1, s, 0, 0, 0);
      // C-frag: S[j=j0+tj*16+4g+r][i=iw0+c]
      float p0 = __expf(s[0]), p1 = __expf(s[1]), p2 = __expf(s[2]), p3 = __expf(s[3]);
      lc += (p0 + p1) + (p2 + p3);
      sPT[wave][c][tj * 8 + 2 * g] = pk_bf16(p0, p1);
      sPT[wave][c][tj * 8 + 2 * g + 1] = pk_bf16(p2, p3);
    }
#pragma unroll
    for (int ks = 0; ks < 2; ++ks) {
      bf16x8 ap = *(const bf16x8*)&sPT[wave][c][ks * 16 + 4 * g];
#pragma unroll
      for (int dt = 0; dt < 4; ++dt) {
        bf16x8 bv = *(const bf16x8*)(VT + (size_t)(dt * 16 + c) * NPOS + j0 + ks * 32 + 8 * g);
        o[dt] = __builtin_amdgcn_mfma_f32_16x16x32_bf16(ap, bv, o[dt], 0, 0, 0);
      }
    }
  }
  lc += __shfl_xor(lc, 16);
  lc += __shfl_xor(lc, 32);
  int gi = chunk * 8 + bh;
  if (lane < 16) Gl[(size_t)gi * MPOS + iw0 + c] = lc;
  float* gp = Gc + ((size_t)gi * MPOS + iw0) * 64;
#pragma unroll
  for (int dt = 0; dt < 4; ++dt)
#pragma unroll
    for (int r = 0; r < 4; ++r)
      gp[(size_t)(4 * g + r) * 64 + dt * 16 + c] = o[dt][r];
}

// ---------------- combine col partials + map_out projection ----------------
__global__ __launch_bounds__(256) void k_map_out(const float* __restrict__ Gc,
                                                 const float* __restrict__ Gl,
                                                 const float* __restrict__ mow,
                                                 float* __restrict__ out2) {
  int m = blockIdx.x, b = blockIdx.y, t = threadIdx.x;
  __shared__ float sMA[256];
  __shared__ float sL[4];
  if (t < 4) {
    float l = 0.f;
#pragma unroll
    for (int ch = 0; ch < JSPLIT; ++ch) l += Gl[(size_t)(ch * 8 + b * 4 + t) * MPOS + m];
    sL[t] = 1.f / l;
  }
  __syncthreads();
  {
    int head = t & 3, dh = t >> 2;  // merged channel c = dh*4+head = t
    int bh = b * 4 + head;
    float a = 0.f;
#pragma unroll
    for (int ch = 0; ch < JSPLIT; ++ch)
      a += Gc[((size_t)(ch * 8 + bh) * MPOS + m) * 64 + dh];
    sMA[t] = a * sL[head];
  }
  __syncthreads();
  if (t < 64) {
    const float* wr = mow + t * 256;
    float acc = 0.f;
#pragma unroll 4
    for (int c = 0; c < 256; ++c) acc += wr[c] * sMA[c];
    out2[((size_t)b * 64 + t) * MPOS + m] = acc;
  }
}

// ---------------- pointwise out GEMM: [128,256] x dwo -> out1 --------------
__global__ __launch_bounds__(256) void k_pw_out(const float* __restrict__ dwo,
                                                const float* __restrict__ pw,
                                                float* __restrict__ out1) {
  __shared__ __align__(16) float sA[128][68];
  __shared__ __align__(16) float sW[128][68];
  int n0 = blockIdx.x * 64, co0 = blockIdx.y * 64, b = blockIdx.z;
  int t = threadIdx.x;
  int tx = t & 15, ty = t >> 4;
  float acc[4][4] = {};
  for (int kk = 0; kk < 2; ++kk) {
    __syncthreads();
#pragma unroll
    for (int r = 0; r < 32; ++r) {
      int e = r * 256 + t;
      int k = e >> 6, n = e & 63;
      sA[k][n] = dwo[((size_t)b * INNER + kk * 128 + k) * NPOS + n0 + n];
    }
#pragma unroll
    for (int r = 0; r < 32; ++r) {
      int e = r * 256 + t;
      int k = e & 127, co = e >> 7;
      sW[k][co] = pw[(size_t)(co0 + co) * INNER + kk * 128 + k];
    }
    __syncthreads();
#pragma unroll 4
    for (int k = 0; k < 128; ++k) {
      float4 a = *(const float4*)&sA[k][tx * 4];
      float4 wv = *(const float4*)&sW[k][ty * 4];
      float av[4] = {a.x, a.y, a.z, a.w};
      float wvv[4] = {wv.x, wv.y, wv.z, wv.w};
#pragma unroll
      for (int i = 0; i < 4; ++i)
#pragma unroll
        for (int j = 0; j < 4; ++j) acc[i][j] += wvv[i] * av[j];
    }
  }
#pragma unroll
  for (int i = 0; i < 4; ++i) {
    int co = co0 + ty * 4 + i;
#pragma unroll
    for (int j = 0; j < 4; ++j) {
      int n = n0 + tx * 4 + j;
      out1[((size_t)b * 128 + co) * NPOS + n] = acc[i][j];
    }
  }
}

extern "C" void kernel_launch(void* const* d_in, const int* in_sizes, int n_in,
                              void* d_out, int out_size, void* d_ws, size_t ws_size,
                              hipStream_t stream) {
  const float* feat = (const float*)d_in[0];
  const float* smap = (const float*)d_in[1];
  const float* fqv_dw = (const float*)d_in[2];
  const float* fqv_pw = (const float*)d_in[3];
  const float* fout_dw = (const float*)d_in[4];
  const float* fout_pw = (const float*)d_in[5];
  const float* mqv_w = (const float*)d_in[6];
  const float* mout_w = (const float*)d_in[7];

  float* out = (float*)d_out;
  float* out1 = out;                              // [2,128,24,24,24]
  float* out2 = out + (size_t)BB * 128 * NPOS;    // [2,64,8,8,8]

  const size_t QV = (size_t)BB * HEADS * NPOS * DH;   // 7,077,888
  const size_t MQV = (size_t)BB * HEADS * MPOS * DH;  // 262,144
  float* ws = (float*)d_ws;
  float* F = ws;                                       // fp32 attn row output (28.3 MB)
  unsigned short* fqb = (unsigned short*)(ws + QV);    // bf16 [bh][j][d]
  unsigned short* fvTb = fqb + QV;                     // bf16 [bh][d][j]
  unsigned short* mapqb = fvTb + QV;                   // bf16 [bh][i][d] (scaled)
  unsigned short* mapvTb = mapqb + MQV;                // bf16 [bh][d][i]
  float* Gc = (float*)(mapvTb + MQV);                  // [JSPLIT*8][512][64]
  float* Gl = Gc + (size_t)JSPLIT * 8 * MPOS * 64;     // [JSPLIT*8][512]
  float* dwo = (float*)fqb;  // reuse fqb+fvTb (28.3 MB) after col pass
  float* dwt = out1;         // depthwise-1 output lives in out1 region

  k_map_qv<<<dim3(BB * MPOS), dim3(512), 0, stream>>>(smap, mqv_w, mapqb, mapvTb);
  k_dw<<<dim3(BB * CH_FEAT * NPOS / 256), dim3(256), 0, stream>>>(feat, fqv_dw, dwt, CH_FEAT, 0);
  k_pw_qv<<<dim3(NPOS / 64, 8, BB), dim3(256), 0, stream>>>(dwt, fqv_pw, fqb, fvTb);
  k_attn_row<<<dim3(NPOS / 64, BB * HEADS), dim3(256), 0, stream>>>(fqb, mapqb, mapvTb, F);
  k_attn_col<<<dim3(MPOS / 64, BB * HEADS, JSPLIT), dim3(256), 0, stream>>>(fqb, fvTb, mapqb, Gc, Gl);
  k_map_out<<<dim3(MPOS, BB), dim3(256), 0, stream>>>(Gc, Gl, mout_w, out2);
  k_dw<<<dim3(BB * INNER * NPOS / 256), dim3(256), 0, stream>>>(F, fout_dw, dwo, INNER, 1);
  k_pw_out<<<dim3(NPOS / 64, 2, BB), dim3(256), 0, stream>>>(dwo, fout_pw, out1);
}

// Round 5
// 374.636 us; speedup vs baseline: 11.5904x; 1.3316x over previous
//
#include <hip/hip_runtime.h>

#define BB 2
#define CH_FEAT 128
#define HEADS 4
#define DH 64
#define INNER 256
#define NPOS 13824   // 24^3
#define MPOS 512     // 8^3
#define DSZ 24
#define JSPLIT 27    // col-pass j chunks
#define JCHUNK (NPOS / JSPLIT)  // 512

typedef __attribute__((ext_vector_type(8))) short bf16x8;
typedef __attribute__((ext_vector_type(4))) float f32x4;

__device__ inline unsigned short bf16_rn(float x) {
  unsigned u = __builtin_bit_cast(unsigned, x);
  u += 0x7FFF + ((u >> 16) & 1);
  return (unsigned short)(u >> 16);
}
__device__ inline unsigned pk_bf16(float a, float b) {
  return (unsigned)bf16_rn(a) | ((unsigned)bf16_rn(b) << 16);
}

// async global->LDS 16B (dest must be wave-uniform base + lane*16)
#define GL2LDS(g, l)                                                        \
  __builtin_amdgcn_global_load_lds(                                         \
      (const __attribute__((address_space(1))) void*)(g),                   \
      (__attribute__((address_space(3))) void*)(l), 16, 0, 0)

// swizzled read of a 16B fragment from a [64 rows][128B] LDS tile
__device__ inline bf16x8 lds_frag(const char* tile, int row, int colb) {
  return *(const bf16x8*)(tile + row * 128 + (colb ^ ((row & 7) << 4)));
}

// ---------------- map q/v projection -> bf16 mapq [bh][m][d], mapv^T [bh][d][m]
__global__ __launch_bounds__(512) void k_map_qv(const float* __restrict__ smap,
                                                const float* __restrict__ w,
                                                unsigned short* __restrict__ mapqb,
                                                unsigned short* __restrict__ mapvTb) {
  int bm = blockIdx.x;
  int b = bm >> 9, m = bm & 511;
  __shared__ float s[64];
  int t = threadIdx.x;
  if (t < 64) s[t] = smap[(size_t)(b * 64 + t) * MPOS + m];
  __syncthreads();
  const float* wr = w + t * 64;
  float acc = 0.f;
#pragma unroll
  for (int c = 0; c < 64; ++c) acc += wr[c] * s[c];
  int qv = t >> 8, c2 = t & 255, head = c2 & 3, dh = c2 >> 2;
  int bh = b * HEADS + head;
  if (qv == 0)
    mapqb[((size_t)bh * MPOS + m) * 64 + dh] = bf16_rn(acc * 0.125f);  // fold scale
  else
    mapvTb[((size_t)bh * 64 + dh) * MPOS + m] = bf16_rn(acc);
}

// ---------------- depthwise 3x3x3 SAME conv; optional head-merge channel remap
__global__ __launch_bounds__(256) void k_dw(const float* __restrict__ in,
                                            const float* __restrict__ w,
                                            float* __restrict__ out, int C, int remap) {
  int idx = blockIdx.x * 256 + threadIdx.x;
  int n = idx % NPOS;
  int bc = idx / NPOS;
  int c = bc % C, b = bc / C;
  int cm = remap ? ((c & 63) * 4 + (c >> 6)) : c;
  int x = n % DSZ, y = (n / DSZ) % DSZ, z = n / (DSZ * DSZ);
  const float* wr = w + cm * 27;
  const float* ip = in + (size_t)bc * NPOS;
  float acc = 0.f;
#pragma unroll
  for (int dz = -1; dz <= 1; ++dz) {
    int zz = z + dz;
    if (zz < 0 || zz >= DSZ) continue;
#pragma unroll
    for (int dy = -1; dy <= 1; ++dy) {
      int yy = y + dy;
      if (yy < 0 || yy >= DSZ) continue;
#pragma unroll
      for (int dx = -1; dx <= 1; ++dx) {
        int xx = x + dx;
        if (xx < 0 || xx >= DSZ) continue;
        acc += wr[(dz + 1) * 9 + (dy + 1) * 3 + (dx + 1)] *
               ip[(zz * DSZ + yy) * DSZ + xx];
      }
    }
  }
  out[((size_t)b * C + cm) * NPOS + n] = acc;
}

// ---------------- pointwise qv GEMM -> fq bf16 [bh][j][d], fv^T bf16 [bh][d][j]
__global__ __launch_bounds__(256) void k_pw_qv(const float* __restrict__ dwt,
                                               const float* __restrict__ pw,
                                               unsigned short* __restrict__ fqb,
                                               unsigned short* __restrict__ fvTb) {
  __shared__ __align__(16) float sA[128][68];
  __shared__ __align__(16) float sW[128][68];
  int n0 = blockIdx.x * 64, co0 = blockIdx.y * 64, b = blockIdx.z;
  int t = threadIdx.x;
#pragma unroll
  for (int r = 0; r < 32; ++r) {
    int e = r * 256 + t;
    int k = e >> 6, n = e & 63;
    sA[k][n] = dwt[((size_t)b * CH_FEAT + k) * NPOS + n0 + n];
  }
#pragma unroll
  for (int r = 0; r < 32; ++r) {
    int e = r * 256 + t;
    int k = e & 127, co = e >> 7;
    sW[k][co] = pw[(size_t)(co0 + co) * CH_FEAT + k];
  }
  __syncthreads();
  int tx = t & 15, ty = t >> 4;
  float acc[4][4] = {};
#pragma unroll 4
  for (int k = 0; k < 128; ++k) {
    float4 a = *(const float4*)&sA[k][tx * 4];
    float4 wv = *(const float4*)&sW[k][ty * 4];
    float av[4] = {a.x, a.y, a.z, a.w};
    float wvv[4] = {wv.x, wv.y, wv.z, wv.w};
#pragma unroll
    for (int i = 0; i < 4; ++i)
#pragma unroll
      for (int j = 0; j < 4; ++j) acc[i][j] += wvv[i] * av[j];
  }
#pragma unroll
  for (int i = 0; i < 4; ++i) {
    int co = co0 + ty * 4 + i;
    int qv = co >> 8, c2 = co & 255, head = c2 & 3, dh = c2 >> 2;
    int bh = b * HEADS + head;
    int n = n0 + tx * 4;
    if (qv == 0) {
      unsigned short* dst = fqb + ((size_t)bh * NPOS + n) * 64 + dh;
#pragma unroll
      for (int j = 0; j < 4; ++j) dst[(size_t)j * 64] = bf16_rn(acc[i][j]);
    } else {
      uint2 wv2;
      wv2.x = pk_bf16(acc[i][0], acc[i][1]);
      wv2.y = pk_bf16(acc[i][2], acc[i][3]);
      *(uint2*)(fvTb + ((size_t)bh * 64 + dh) * NPOS + n) = wv2;
    }
  }
}

// ---------------- MFMA attention row pass (LDS-staged, double-buffered) ----
// block: 4 waves x 32 rows = 128 feat rows; K/V tiles staged per 64-i chunk
__global__ __launch_bounds__(256) void k_attn_row(const unsigned short* __restrict__ fqb,
                                                  const unsigned short* __restrict__ mapqb,
                                                  const unsigned short* __restrict__ mapvTb,
                                                  float* __restrict__ F) {
  __shared__ __align__(16) char sK[2][8192];  // K chunk [64 i][64 d] bf16, swizzled
  __shared__ __align__(16) char sV[2][8192];  // V^T chunk [64 d][64 i] bf16, swizzled
  __shared__ __align__(16) unsigned sP[4][2][16][36];
  __shared__ float sL[4][2][16];
  int t = threadIdx.x, wave = t >> 6, lane = t & 63, g = lane >> 4, c = lane & 15;
  int bh = blockIdx.y;
  int j0 = blockIdx.x * 128 + wave * 32;

  const char* Kg = (const char*)(mapqb + (size_t)bh * MPOS * 64);
  const char* Vg = (const char*)(mapvTb + (size_t)bh * 64 * MPOS);

  const unsigned short* fqp = fqb + ((size_t)bh * NPOS + j0 + c) * 64 + 8 * g;
  bf16x8 bq00 = *(const bf16x8*)(fqp);
  bf16x8 bq01 = *(const bf16x8*)(fqp + 32);
  bf16x8 bq10 = *(const bf16x8*)(fqp + 16 * 64);
  bf16x8 bq11 = *(const bf16x8*)(fqp + 16 * 64 + 32);

  f32x4 o[2][4];
#pragma unroll
  for (int jf = 0; jf < 2; ++jf)
#pragma unroll
    for (int dt = 0; dt < 4; ++dt) o[jf][dt] = (f32x4){0.f, 0.f, 0.f, 0.f};
  float ls0 = 0.f, ls1 = 0.f;

  // stage chunk 0
#pragma unroll
  for (int p = 0; p < 2; ++p) {
    int oo = p * 4096 + t * 16;
    int row = oo >> 7, col = (oo & 127) ^ (((oo >> 7) & 7) << 4);
    GL2LDS(Kg + (size_t)row * 128 + col, sK[0] + oo);
    GL2LDS(Vg + (size_t)row * 1024 + col, sV[0] + oo);
  }
  __syncthreads();

  for (int ic = 0; ic < 8; ++ic) {
    const char* Kt = sK[ic & 1];
    const char* Vt = sV[ic & 1];
    if (ic < 7) {
      int ibase = (ic + 1) * 64;
#pragma unroll
      for (int p = 0; p < 2; ++p) {
        int oo = p * 4096 + t * 16;
        int row = oo >> 7, col = (oo & 127) ^ (((oo >> 7) & 7) << 4);
        GL2LDS(Kg + (size_t)(ibase + row) * 128 + col, sK[(ic + 1) & 1] + oo);
        GL2LDS(Vg + (size_t)row * 1024 + ibase * 2 + col, sV[(ic + 1) & 1] + oo);
      }
    }
#pragma unroll
    for (int ti = 0; ti < 4; ++ti) {
      bf16x8 a0 = lds_frag(Kt, ti * 16 + c, 16 * g);
      bf16x8 a1 = lds_frag(Kt, ti * 16 + c, 64 + 16 * g);
      f32x4 s0 = {0.f, 0.f, 0.f, 0.f}, s1 = {0.f, 0.f, 0.f, 0.f};
      s0 = __builtin_amdgcn_mfma_f32_16x16x32_bf16(a0, bq00, s0, 0, 0, 0);
      s0 = __builtin_amdgcn_mfma_f32_16x16x32_bf16(a1, bq01, s0, 0, 0, 0);
      s1 = __builtin_amdgcn_mfma_f32_16x16x32_bf16(a0, bq10, s1, 0, 0, 0);
      s1 = __builtin_amdgcn_mfma_f32_16x16x32_bf16(a1, bq11, s1, 0, 0, 0);
      float p0 = __expf(s0[0]), p1 = __expf(s0[1]), p2 = __expf(s0[2]), p3 = __expf(s0[3]);
      ls0 += (p0 + p1) + (p2 + p3);
      sP[wave][0][c][ti * 8 + 2 * g] = pk_bf16(p0, p1);
      sP[wave][0][c][ti * 8 + 2 * g + 1] = pk_bf16(p2, p3);
      float q0 = __expf(s1[0]), q1 = __expf(s1[1]), q2 = __expf(s1[2]), q3 = __expf(s1[3]);
      ls1 += (q0 + q1) + (q2 + q3);
      sP[wave][1][c][ti * 8 + 2 * g] = pk_bf16(q0, q1);
      sP[wave][1][c][ti * 8 + 2 * g + 1] = pk_bf16(q2, q3);
    }
#pragma unroll
    for (int ks = 0; ks < 2; ++ks) {
      bf16x8 ap0 = *(const bf16x8*)&sP[wave][0][c][ks * 16 + 4 * g];
      bf16x8 ap1 = *(const bf16x8*)&sP[wave][1][c][ks * 16 + 4 * g];
#pragma unroll
      for (int dt = 0; dt < 4; ++dt) {
        bf16x8 bv = lds_frag(Vt, dt * 16 + c, ks * 64 + 16 * g);
        o[0][dt] = __builtin_amdgcn_mfma_f32_16x16x32_bf16(ap0, bv, o[0][dt], 0, 0, 0);
        o[1][dt] = __builtin_amdgcn_mfma_f32_16x16x32_bf16(ap1, bv, o[1][dt], 0, 0, 0);
      }
    }
    __syncthreads();
  }

  ls0 += __shfl_xor(ls0, 16); ls0 += __shfl_xor(ls0, 32);
  ls1 += __shfl_xor(ls1, 16); ls1 += __shfl_xor(ls1, 32);
  if (g == 0) { sL[wave][0][c] = 1.f / ls0; sL[wave][1][c] = 1.f / ls1; }
  int b = bh >> 2, head = bh & 3;
#pragma unroll
  for (int jf = 0; jf < 2; ++jf) {
    float rl0 = sL[wave][jf][4 * g + 0], rl1 = sL[wave][jf][4 * g + 1];
    float rl2 = sL[wave][jf][4 * g + 2], rl3 = sL[wave][jf][4 * g + 3];
#pragma unroll
    for (int dt = 0; dt < 4; ++dt) {
      float4 v = make_float4(o[jf][dt][0] * rl0, o[jf][dt][1] * rl1,
                             o[jf][dt][2] * rl2, o[jf][dt][3] * rl3);
      *(float4*)(F + ((size_t)b * INNER + head * 64 + dt * 16 + c) * NPOS +
                 j0 + jf * 16 + 4 * g) = v;
    }
  }
}

// ---------------- MFMA attention col pass (LDS-staged, j-chunked) ----------
// block: 4 waves x 32 map cols = 128 i; fq/fv^T tiles staged per 64-j subchunk
__global__ __launch_bounds__(256) void k_attn_col(const unsigned short* __restrict__ fqb,
                                                  const unsigned short* __restrict__ fvTb,
                                                  const unsigned short* __restrict__ mapqb,
                                                  float* __restrict__ Gc,
                                                  float* __restrict__ Gl) {
  __shared__ __align__(16) char sQ[2][8192];  // fq chunk [64 j][64 d]
  __shared__ __align__(16) char sV[2][8192];  // fv^T chunk [64 d][64 j]
  __shared__ __align__(16) unsigned sP[4][2][16][36];
  int t = threadIdx.x, wave = t >> 6, lane = t & 63, g = lane >> 4, c = lane & 15;
  int bh = blockIdx.y, chunk = blockIdx.z;
  int i0 = blockIdx.x * 128 + wave * 32;
  int jb = chunk * JCHUNK;

  const char* Qg = (const char*)(fqb + (size_t)bh * NPOS * 64);
  const char* Vg = (const char*)(fvTb + (size_t)bh * 64 * NPOS);

  const unsigned short* kp = mapqb + ((size_t)bh * MPOS + i0 + c) * 64 + 8 * g;
  bf16x8 bm00 = *(const bf16x8*)(kp);
  bf16x8 bm01 = *(const bf16x8*)(kp + 32);
  bf16x8 bm10 = *(const bf16x8*)(kp + 16 * 64);
  bf16x8 bm11 = *(const bf16x8*)(kp + 16 * 64 + 32);

  f32x4 o[2][4];
#pragma unroll
  for (int f = 0; f < 2; ++f)
#pragma unroll
    for (int dt = 0; dt < 4; ++dt) o[f][dt] = (f32x4){0.f, 0.f, 0.f, 0.f};
  float lc0 = 0.f, lc1 = 0.f;

#pragma unroll
  for (int p = 0; p < 2; ++p) {
    int oo = p * 4096 + t * 16;
    int row = oo >> 7, col = (oo & 127) ^ (((oo >> 7) & 7) << 4);
    GL2LDS(Qg + (size_t)(jb + row) * 128 + col, sQ[0] + oo);
    GL2LDS(Vg + (size_t)row * (NPOS * 2) + jb * 2 + col, sV[0] + oo);
  }
  __syncthreads();

  for (int jc = 0; jc < JCHUNK / 64; ++jc) {
    const char* Qt = sQ[jc & 1];
    const char* Vt = sV[jc & 1];
    if (jc < JCHUNK / 64 - 1) {
      int jbase = jb + (jc + 1) * 64;
#pragma unroll
      for (int p = 0; p < 2; ++p) {
        int oo = p * 4096 + t * 16;
        int row = oo >> 7, col = (oo & 127) ^ (((oo >> 7) & 7) << 4);
        GL2LDS(Qg + (size_t)(jbase + row) * 128 + col, sQ[(jc + 1) & 1] + oo);
        GL2LDS(Vg + (size_t)row * (NPOS * 2) + jbase * 2 + col, sV[(jc + 1) & 1] + oo);
      }
    }
#pragma unroll
    for (int tj = 0; tj < 4; ++tj) {
      bf16x8 a0 = lds_frag(Qt, tj * 16 + c, 16 * g);
      bf16x8 a1 = lds_frag(Qt, tj * 16 + c, 64 + 16 * g);
      f32x4 s0 = {0.f, 0.f, 0.f, 0.f}, s1 = {0.f, 0.f, 0.f, 0.f};
      s0 = __builtin_amdgcn_mfma_f32_16x16x32_bf16(a0, bm00, s0, 0, 0, 0);
      s0 = __builtin_amdgcn_mfma_f32_16x16x32_bf16(a1, bm01, s0, 0, 0, 0);
      s1 = __builtin_amdgcn_mfma_f32_16x16x32_bf16(a0, bm10, s1, 0, 0, 0);
      s1 = __builtin_amdgcn_mfma_f32_16x16x32_bf16(a1, bm11, s1, 0, 0, 0);
      float p0 = __expf(s0[0]), p1 = __expf(s0[1]), p2 = __expf(s0[2]), p3 = __expf(s0[3]);
      lc0 += (p0 + p1) + (p2 + p3);
      sP[wave][0][c][tj * 8 + 2 * g] = pk_bf16(p0, p1);
      sP[wave][0][c][tj * 8 + 2 * g + 1] = pk_bf16(p2, p3);
      float q0 = __expf(s1[0]), q1 = __expf(s1[1]), q2 = __expf(s1[2]), q3 = __expf(s1[3]);
      lc1 += (q0 + q1) + (q2 + q3);
      sP[wave][1][c][tj * 8 + 2 * g] = pk_bf16(q0, q1);
      sP[wave][1][c][tj * 8 + 2 * g + 1] = pk_bf16(q2, q3);
    }
#pragma unroll
    for (int ks = 0; ks < 2; ++ks) {
      bf16x8 ap0 = *(const bf16x8*)&sP[wave][0][c][ks * 16 + 4 * g];
      bf16x8 ap1 = *(const bf16x8*)&sP[wave][1][c][ks * 16 + 4 * g];
#pragma unroll
      for (int dt = 0; dt < 4; ++dt) {
        bf16x8 bv = lds_frag(Vt, dt * 16 + c, ks * 64 + 16 * g);
        o[0][dt] = __builtin_amdgcn_mfma_f32_16x16x32_bf16(ap0, bv, o[0][dt], 0, 0, 0);
        o[1][dt] = __builtin_amdgcn_mfma_f32_16x16x32_bf16(ap1, bv, o[1][dt], 0, 0, 0);
      }
    }
    __syncthreads();
  }

  lc0 += __shfl_xor(lc0, 16); lc0 += __shfl_xor(lc0, 32);
  lc1 += __shfl_xor(lc1, 16); lc1 += __shfl_xor(lc1, 32);
  int gi = chunk * 8 + bh;
  if (g == 0) {
    Gl[(size_t)gi * MPOS + i0 + c] = lc0;
    Gl[(size_t)gi * MPOS + i0 + 16 + c] = lc1;
  }
  float* gp = Gc + ((size_t)gi * MPOS + i0) * 64;
#pragma unroll
  for (int f = 0; f < 2; ++f)
#pragma unroll
    for (int dt = 0; dt < 4; ++dt)
#pragma unroll
      for (int r = 0; r < 4; ++r)
        gp[(size_t)(f * 16 + 4 * g + r) * 64 + dt * 16 + c] = o[f][dt][r];
}

// ---------------- combine col partials + map_out projection ----------------
__global__ __launch_bounds__(256) void k_map_out(const float* __restrict__ Gc,
                                                 const float* __restrict__ Gl,
                                                 const float* __restrict__ mow,
                                                 float* __restrict__ out2) {
  int m = blockIdx.x, b = blockIdx.y, t = threadIdx.x;
  __shared__ float sMA[256];
  __shared__ float sL[4];
  if (t < 4) {
    float l = 0.f;
#pragma unroll 4
    for (int ch = 0; ch < JSPLIT; ++ch) l += Gl[(size_t)(ch * 8 + b * 4 + t) * MPOS + m];
    sL[t] = 1.f / l;
  }
  __syncthreads();
  {
    int head = t & 3, dh = t >> 2;
    int bh = b * 4 + head;
    float a = 0.f;
#pragma unroll 4
    for (int ch = 0; ch < JSPLIT; ++ch)
      a += Gc[((size_t)(ch * 8 + bh) * MPOS + m) * 64 + dh];
    sMA[t] = a * sL[head];
  }
  __syncthreads();
  if (t < 64) {
    const float* wr = mow + t * 256;
    float acc = 0.f;
#pragma unroll 4
    for (int c = 0; c < 256; ++c) acc += wr[c] * sMA[c];
    out2[((size_t)b * 64 + t) * MPOS + m] = acc;
  }
}

// ---------------- pointwise out GEMM: [128,256] x dwo -> out1 --------------
__global__ __launch_bounds__(256) void k_pw_out(const float* __restrict__ dwo,
                                                const float* __restrict__ pw,
                                                float* __restrict__ out1) {
  __shared__ __align__(16) float sA[128][68];
  __shared__ __align__(16) float sW[128][68];
  int n0 = blockIdx.x * 64, co0 = blockIdx.y * 64, b = blockIdx.z;
  int t = threadIdx.x;
  int tx = t & 15, ty = t >> 4;
  float acc[4][4] = {};
  for (int kk = 0; kk < 2; ++kk) {
    __syncthreads();
#pragma unroll
    for (int r = 0; r < 32; ++r) {
      int e = r * 256 + t;
      int k = e >> 6, n = e & 63;
      sA[k][n] = dwo[((size_t)b * INNER + kk * 128 + k) * NPOS + n0 + n];
    }
#pragma unroll
    for (int r = 0; r < 32; ++r) {
      int e = r * 256 + t;
      int k = e & 127, co = e >> 7;
      sW[k][co] = pw[(size_t)(co0 + co) * INNER + kk * 128 + k];
    }
    __syncthreads();
#pragma unroll 4
    for (int k = 0; k < 128; ++k) {
      float4 a = *(const float4*)&sA[k][tx * 4];
      float4 wv = *(const float4*)&sW[k][ty * 4];
      float av[4] = {a.x, a.y, a.z, a.w};
      float wvv[4] = {wv.x, wv.y, wv.z, wv.w};
#pragma unroll
      for (int i = 0; i < 4; ++i)
#pragma unroll
        for (int j = 0; j < 4; ++j) acc[i][j] += wvv[i] * av[j];
    }
  }
#pragma unroll
  for (int i = 0; i < 4; ++i) {
    int co = co0 + ty * 4 + i;
#pragma unroll
    for (int j = 0; j < 4; ++j) {
      int n = n0 + tx * 4 + j;
      out1[((size_t)b * 128 + co) * NPOS + n] = acc[i][j];
    }
  }
}

extern "C" void kernel_launch(void* const* d_in, const int* in_sizes, int n_in,
                              void* d_out, int out_size, void* d_ws, size_t ws_size,
                              hipStream_t stream) {
  const float* feat = (const float*)d_in[0];
  const float* smap = (const float*)d_in[1];
  const float* fqv_dw = (const float*)d_in[2];
  const float* fqv_pw = (const float*)d_in[3];
  const float* fout_dw = (const float*)d_in[4];
  const float* fout_pw = (const float*)d_in[5];
  const float* mqv_w = (const float*)d_in[6];
  const float* mout_w = (const float*)d_in[7];

  float* out = (float*)d_out;
  float* out1 = out;                              // [2,128,24,24,24]
  float* out2 = out + (size_t)BB * 128 * NPOS;    // [2,64,8,8,8]

  const size_t QV = (size_t)BB * HEADS * NPOS * DH;   // 7,077,888
  const size_t MQV = (size_t)BB * HEADS * MPOS * DH;  // 262,144
  float* ws = (float*)d_ws;
  float* F = ws;                                       // fp32 attn row output
  unsigned short* fqb = (unsigned short*)(ws + QV);    // bf16 [bh][j][d]
  unsigned short* fvTb = fqb + QV;                     // bf16 [bh][d][j]
  unsigned short* mapqb = fvTb + QV;                   // bf16 [bh][i][d] (scaled)
  unsigned short* mapvTb = mapqb + MQV;                // bf16 [bh][d][i]
  float* Gc = (float*)(mapvTb + MQV);                  // [JSPLIT*8][512][64]
  float* Gl = Gc + (size_t)JSPLIT * 8 * MPOS * 64;     // [JSPLIT*8][512]
  float* dwo = (float*)fqb;  // reuse fqb+fvTb (28.3 MB) after col pass
  float* dwt = out1;         // depthwise-1 output lives in out1 region

  k_map_qv<<<dim3(BB * MPOS), dim3(512), 0, stream>>>(smap, mqv_w, mapqb, mapvTb);
  k_dw<<<dim3(BB * CH_FEAT * NPOS / 256), dim3(256), 0, stream>>>(feat, fqv_dw, dwt, CH_FEAT, 0);
  k_pw_qv<<<dim3(NPOS / 64, 8, BB), dim3(256), 0, stream>>>(dwt, fqv_pw, fqb, fvTb);
  k_attn_row<<<dim3(NPOS / 128, BB * HEADS), dim3(256), 0, stream>>>(fqb, mapqb, mapvTb, F);
  k_attn_col<<<dim3(MPOS / 128, BB * HEADS, JSPLIT), dim3(256), 0, stream>>>(fqb, fvTb, mapqb, Gc, Gl);
  k_map_out<<<dim3(MPOS, BB), dim3(256), 0, stream>>>(Gc, Gl, mout_w, out2);
  k_dw<<<dim3(BB * INNER * NPOS / 256), dim3(256), 0, stream>>>(F, fout_dw, dwo, INNER, 1);
  k_pw_out<<<dim3(NPOS / 64, 2, BB), dim3(256), 0, stream>>>(dwo, fout_pw, out1);
}

// Round 6
// 274.748 us; speedup vs baseline: 15.8043x; 1.3636x over previous
//
#include <hip/hip_runtime.h>

#define BB 2
#define CH_FEAT 128
#define HEADS 4
#define DH 64
#define INNER 256
#define NPOS 13824   // 24^3
#define MPOS 512     // 8^3
#define DSZ 24
#define JSPLIT 27    // col-pass j chunks
#define JCHUNK (NPOS / JSPLIT)  // 512

typedef __attribute__((ext_vector_type(8))) short bf16x8;
typedef __attribute__((ext_vector_type(4))) float f32x4;

__device__ inline unsigned short bf16_rn(float x) {
  unsigned u = __builtin_bit_cast(unsigned, x);
  u += 0x7FFF + ((u >> 16) & 1);
  return (unsigned short)(u >> 16);
}
__device__ inline unsigned pk_bf16(float a, float b) {
  return (unsigned)bf16_rn(a) | ((unsigned)bf16_rn(b) << 16);
}

// async global->LDS 16B (dest must be wave-uniform base + lane*16)
#define GL2LDS(g, l)                                                        \
  __builtin_amdgcn_global_load_lds(                                         \
      (const __attribute__((address_space(1))) void*)(g),                   \
      (__attribute__((address_space(3))) void*)(l), 16, 0, 0)

// swizzled read of a 16B fragment from a [64 rows][128B] LDS tile
__device__ inline bf16x8 lds_frag(const char* tile, int row, int colb) {
  return *(const bf16x8*)(tile + row * 128 + (colb ^ ((row & 7) << 4)));
}

// ---------------- map q/v projection -> bf16 mapq [bh][m][d], mapv^T [bh][d][m]
__global__ __launch_bounds__(512) void k_map_qv(const float* __restrict__ smap,
                                                const float* __restrict__ w,
                                                unsigned short* __restrict__ mapqb,
                                                unsigned short* __restrict__ mapvTb) {
  int bm = blockIdx.x;
  int b = bm >> 9, m = bm & 511;
  __shared__ float s[64];
  int t = threadIdx.x;
  if (t < 64) s[t] = smap[(size_t)(b * 64 + t) * MPOS + m];
  __syncthreads();
  const float* wr = w + t * 64;
  float acc = 0.f;
#pragma unroll
  for (int c = 0; c < 64; ++c) acc += wr[c] * s[c];
  int qv = t >> 8, c2 = t & 255, head = c2 & 3, dh = c2 >> 2;
  int bh = b * HEADS + head;
  if (qv == 0)
    mapqb[((size_t)bh * MPOS + m) * 64 + dh] = bf16_rn(acc * 0.125f);  // fold scale
  else
    mapvTb[((size_t)bh * 64 + dh) * MPOS + m] = bf16_rn(acc);
}

// ---------------- depthwise 3x3x3 SAME conv, register-rolling x-march ------
// block = 576 threads = one (b,c) channel; thread owns (y,z), marches x.
__global__ __launch_bounds__(576) void k_dw(const float* __restrict__ in,
                                            const float* __restrict__ w,
                                            float* __restrict__ out, int C, int remap) {
  int t = threadIdx.x;
  int bc = blockIdx.x;
  int c = bc & (C - 1), b = bc / C;
  int cm = remap ? ((c & 63) * 4 + (c >> 6)) : c;  // storage head*64+d -> merged d*4+head
  int y = t % 24, z = t / 24;
  const float* wr = w + cm * 27;
  const float* ip = in + (size_t)bc * NPOS;

  float wm[9][3];
  int off[9];
#pragma unroll
  for (int dz = 0; dz < 3; ++dz)
#pragma unroll
    for (int dy = 0; dy < 3; ++dy) {
      int r = dz * 3 + dy;
      int zz = z + dz - 1, yy = y + dy - 1;
      float m = ((unsigned)zz < 24u && (unsigned)yy < 24u) ? 1.f : 0.f;
      wm[r][0] = wr[dz * 9 + dy * 3 + 0] * m;
      wm[r][1] = wr[dz * 9 + dy * 3 + 1] * m;
      wm[r][2] = wr[dz * 9 + dy * 3 + 2] * m;
      int zc = min(max(zz, 0), 23), yc = min(max(yy, 0), 23);
      off[r] = (zc * 24 + yc) * 24;
    }

  float4 cur[9], nxt[9];
  float pl[9];
#pragma unroll
  for (int r = 0; r < 9; ++r) {
    pl[r] = 0.f;
    cur[r] = *(const float4*)(ip + off[r]);
    nxt[r] = *(const float4*)(ip + off[r] + 4);
  }

  float* op = out + ((size_t)b * C + cm) * NPOS + (z * 24 + y) * 24;
#pragma unroll
  for (int xc = 0; xc < 6; ++xc) {
    float4 acc;
    acc.x = acc.y = acc.z = acc.w = 0.f;
#pragma unroll
    for (int r = 0; r < 9; ++r) {
      float w0 = wm[r][0], w1 = wm[r][1], w2 = wm[r][2];
      float4 cu = cur[r];
      acc.x += w0 * pl[r] + w1 * cu.x + w2 * cu.y;
      acc.y += w0 * cu.x + w1 * cu.y + w2 * cu.z;
      acc.z += w0 * cu.y + w1 * cu.z + w2 * cu.w;
      acc.w += w0 * cu.z + w1 * cu.w + w2 * nxt[r].x;
    }
    *(float4*)(op + xc * 4) = acc;
    if (xc < 5) {
#pragma unroll
      for (int r = 0; r < 9; ++r) {
        pl[r] = cur[r].w;
        cur[r] = nxt[r];
        nxt[r] = (xc < 4) ? *(const float4*)(ip + off[r] + (xc + 2) * 4)
                          : make_float4(0.f, 0.f, 0.f, 0.f);
      }
    }
  }
}

// ---------------- pointwise qv GEMM -> fq bf16 [bh][j][d], fv^T bf16 [bh][d][j]
__global__ __launch_bounds__(256) void k_pw_qv(const float* __restrict__ dwt,
                                               const float* __restrict__ pw,
                                               unsigned short* __restrict__ fqb,
                                               unsigned short* __restrict__ fvTb) {
  __shared__ __align__(16) float sA[128][68];
  __shared__ __align__(16) float sW[128][68];
  int n0 = blockIdx.x * 64, co0 = blockIdx.y * 64, b = blockIdx.z;
  int t = threadIdx.x;
#pragma unroll
  for (int r = 0; r < 32; ++r) {
    int e = r * 256 + t;
    int k = e >> 6, n = e & 63;
    sA[k][n] = dwt[((size_t)b * CH_FEAT + k) * NPOS + n0 + n];
  }
#pragma unroll
  for (int r = 0; r < 32; ++r) {
    int e = r * 256 + t;
    int k = e & 127, co = e >> 7;
    sW[k][co] = pw[(size_t)(co0 + co) * CH_FEAT + k];
  }
  __syncthreads();
  int tx = t & 15, ty = t >> 4;
  float acc[4][4] = {};
#pragma unroll 4
  for (int k = 0; k < 128; ++k) {
    float4 a = *(const float4*)&sA[k][tx * 4];
    float4 wv = *(const float4*)&sW[k][ty * 4];
    float av[4] = {a.x, a.y, a.z, a.w};
    float wvv[4] = {wv.x, wv.y, wv.z, wv.w};
#pragma unroll
    for (int i = 0; i < 4; ++i)
#pragma unroll
      for (int j = 0; j < 4; ++j) acc[i][j] += wvv[i] * av[j];
  }
#pragma unroll
  for (int i = 0; i < 4; ++i) {
    int co = co0 + ty * 4 + i;
    int qv = co >> 8, c2 = co & 255, head = c2 & 3, dh = c2 >> 2;
    int bh = b * HEADS + head;
    int n = n0 + tx * 4;
    if (qv == 0) {
      unsigned short* dst = fqb + ((size_t)bh * NPOS + n) * 64 + dh;
#pragma unroll
      for (int j = 0; j < 4; ++j) dst[(size_t)j * 64] = bf16_rn(acc[i][j]);
    } else {
      uint2 wv2;
      wv2.x = pk_bf16(acc[i][0], acc[i][1]);
      wv2.y = pk_bf16(acc[i][2], acc[i][3]);
      *(uint2*)(fvTb + ((size_t)bh * 64 + dh) * NPOS + n) = wv2;
    }
  }
}

// ---------------- MFMA attention row pass (LDS-staged, double-buffered) ----
__global__ __launch_bounds__(256) void k_attn_row(const unsigned short* __restrict__ fqb,
                                                  const unsigned short* __restrict__ mapqb,
                                                  const unsigned short* __restrict__ mapvTb,
                                                  float* __restrict__ F) {
  __shared__ __align__(16) char sK[2][8192];
  __shared__ __align__(16) char sV[2][8192];
  __shared__ __align__(16) unsigned sP[4][2][16][36];
  __shared__ float sL[4][2][16];
  int t = threadIdx.x, wave = t >> 6, lane = t & 63, g = lane >> 4, c = lane & 15;
  int bh = blockIdx.y;
  int j0 = blockIdx.x * 128 + wave * 32;

  const char* Kg = (const char*)(mapqb + (size_t)bh * MPOS * 64);
  const char* Vg = (const char*)(mapvTb + (size_t)bh * 64 * MPOS);

  const unsigned short* fqp = fqb + ((size_t)bh * NPOS + j0 + c) * 64 + 8 * g;
  bf16x8 bq00 = *(const bf16x8*)(fqp);
  bf16x8 bq01 = *(const bf16x8*)(fqp + 32);
  bf16x8 bq10 = *(const bf16x8*)(fqp + 16 * 64);
  bf16x8 bq11 = *(const bf16x8*)(fqp + 16 * 64 + 32);

  f32x4 o[2][4];
#pragma unroll
  for (int jf = 0; jf < 2; ++jf)
#pragma unroll
    for (int dt = 0; dt < 4; ++dt) o[jf][dt] = (f32x4){0.f, 0.f, 0.f, 0.f};
  float ls0 = 0.f, ls1 = 0.f;

#pragma unroll
  for (int p = 0; p < 2; ++p) {
    int oo = p * 4096 + t * 16;
    int row = oo >> 7, col = (oo & 127) ^ (((oo >> 7) & 7) << 4);
    GL2LDS(Kg + (size_t)row * 128 + col, sK[0] + oo);
    GL2LDS(Vg + (size_t)row * 1024 + col, sV[0] + oo);
  }
  __syncthreads();

  for (int ic = 0; ic < 8; ++ic) {
    const char* Kt = sK[ic & 1];
    const char* Vt = sV[ic & 1];
    if (ic < 7) {
      int ibase = (ic + 1) * 64;
#pragma unroll
      for (int p = 0; p < 2; ++p) {
        int oo = p * 4096 + t * 16;
        int row = oo >> 7, col = (oo & 127) ^ (((oo >> 7) & 7) << 4);
        GL2LDS(Kg + (size_t)(ibase + row) * 128 + col, sK[(ic + 1) & 1] + oo);
        GL2LDS(Vg + (size_t)row * 1024 + ibase * 2 + col, sV[(ic + 1) & 1] + oo);
      }
    }
#pragma unroll
    for (int ti = 0; ti < 4; ++ti) {
      bf16x8 a0 = lds_frag(Kt, ti * 16 + c, 16 * g);
      bf16x8 a1 = lds_frag(Kt, ti * 16 + c, 64 + 16 * g);
      f32x4 s0 = {0.f, 0.f, 0.f, 0.f}, s1 = {0.f, 0.f, 0.f, 0.f};
      s0 = __builtin_amdgcn_mfma_f32_16x16x32_bf16(a0, bq00, s0, 0, 0, 0);
      s0 = __builtin_amdgcn_mfma_f32_16x16x32_bf16(a1, bq01, s0, 0, 0, 0);
      s1 = __builtin_amdgcn_mfma_f32_16x16x32_bf16(a0, bq10, s1, 0, 0, 0);
      s1 = __builtin_amdgcn_mfma_f32_16x16x32_bf16(a1, bq11, s1, 0, 0, 0);
      float p0 = __expf(s0[0]), p1 = __expf(s0[1]), p2 = __expf(s0[2]), p3 = __expf(s0[3]);
      ls0 += (p0 + p1) + (p2 + p3);
      sP[wave][0][c][ti * 8 + 2 * g] = pk_bf16(p0, p1);
      sP[wave][0][c][ti * 8 + 2 * g + 1] = pk_bf16(p2, p3);
      float q0 = __expf(s1[0]), q1 = __expf(s1[1]), q2 = __expf(s1[2]), q3 = __expf(s1[3]);
      ls1 += (q0 + q1) + (q2 + q3);
      sP[wave][1][c][ti * 8 + 2 * g] = pk_bf16(q0, q1);
      sP[wave][1][c][ti * 8 + 2 * g + 1] = pk_bf16(q2, q3);
    }
#pragma unroll
    for (int ks = 0; ks < 2; ++ks) {
      bf16x8 ap0 = *(const bf16x8*)&sP[wave][0][c][ks * 16 + 4 * g];
      bf16x8 ap1 = *(const bf16x8*)&sP[wave][1][c][ks * 16 + 4 * g];
#pragma unroll
      for (int dt = 0; dt < 4; ++dt) {
        bf16x8 bv = lds_frag(Vt, dt * 16 + c, ks * 64 + 16 * g);
        o[0][dt] = __builtin_amdgcn_mfma_f32_16x16x32_bf16(ap0, bv, o[0][dt], 0, 0, 0);
        o[1][dt] = __builtin_amdgcn_mfma_f32_16x16x32_bf16(ap1, bv, o[1][dt], 0, 0, 0);
      }
    }
    __syncthreads();
  }

  ls0 += __shfl_xor(ls0, 16); ls0 += __shfl_xor(ls0, 32);
  ls1 += __shfl_xor(ls1, 16); ls1 += __shfl_xor(ls1, 32);
  if (g == 0) { sL[wave][0][c] = 1.f / ls0; sL[wave][1][c] = 1.f / ls1; }
  int b = bh >> 2, head = bh & 3;
#pragma unroll
  for (int jf = 0; jf < 2; ++jf) {
    float rl0 = sL[wave][jf][4 * g + 0], rl1 = sL[wave][jf][4 * g + 1];
    float rl2 = sL[wave][jf][4 * g + 2], rl3 = sL[wave][jf][4 * g + 3];
#pragma unroll
    for (int dt = 0; dt < 4; ++dt) {
      float4 v = make_float4(o[jf][dt][0] * rl0, o[jf][dt][1] * rl1,
                             o[jf][dt][2] * rl2, o[jf][dt][3] * rl3);
      *(float4*)(F + ((size_t)b * INNER + head * 64 + dt * 16 + c) * NPOS +
                 j0 + jf * 16 + 4 * g) = v;
    }
  }
}

// ---------------- MFMA attention col pass (LDS-staged, j-chunked) ----------
__global__ __launch_bounds__(256) void k_attn_col(const unsigned short* __restrict__ fqb,
                                                  const unsigned short* __restrict__ fvTb,
                                                  const unsigned short* __restrict__ mapqb,
                                                  float* __restrict__ Gc,
                                                  float* __restrict__ Gl) {
  __shared__ __align__(16) char sQ[2][8192];
  __shared__ __align__(16) char sV[2][8192];
  __shared__ __align__(16) unsigned sP[4][2][16][36];
  int t = threadIdx.x, wave = t >> 6, lane = t & 63, g = lane >> 4, c = lane & 15;
  int bh = blockIdx.y, chunk = blockIdx.z;
  int i0 = blockIdx.x * 128 + wave * 32;
  int jb = chunk * JCHUNK;

  const char* Qg = (const char*)(fqb + (size_t)bh * NPOS * 64);
  const char* Vg = (const char*)(fvTb + (size_t)bh * 64 * NPOS);

  const unsigned short* kp = mapqb + ((size_t)bh * MPOS + i0 + c) * 64 + 8 * g;
  bf16x8 bm00 = *(const bf16x8*)(kp);
  bf16x8 bm01 = *(const bf16x8*)(kp + 32);
  bf16x8 bm10 = *(const bf16x8*)(kp + 16 * 64);
  bf16x8 bm11 = *(const bf16x8*)(kp + 16 * 64 + 32);

  f32x4 o[2][4];
#pragma unroll
  for (int f = 0; f < 2; ++f)
#pragma unroll
    for (int dt = 0; dt < 4; ++dt) o[f][dt] = (f32x4){0.f, 0.f, 0.f, 0.f};
  float lc0 = 0.f, lc1 = 0.f;

#pragma unroll
  for (int p = 0; p < 2; ++p) {
    int oo = p * 4096 + t * 16;
    int row = oo >> 7, col = (oo & 127) ^ (((oo >> 7) & 7) << 4);
    GL2LDS(Qg + (size_t)(jb + row) * 128 + col, sQ[0] + oo);
    GL2LDS(Vg + (size_t)row * (NPOS * 2) + jb * 2 + col, sV[0] + oo);
  }
  __syncthreads();

  for (int jc = 0; jc < JCHUNK / 64; ++jc) {
    const char* Qt = sQ[jc & 1];
    const char* Vt = sV[jc & 1];
    if (jc < JCHUNK / 64 - 1) {
      int jbase = jb + (jc + 1) * 64;
#pragma unroll
      for (int p = 0; p < 2; ++p) {
        int oo = p * 4096 + t * 16;
        int row = oo >> 7, col = (oo & 127) ^ (((oo >> 7) & 7) << 4);
        GL2LDS(Qg + (size_t)(jbase + row) * 128 + col, sQ[(jc + 1) & 1] + oo);
        GL2LDS(Vg + (size_t)row * (NPOS * 2) + jbase * 2 + col, sV[(jc + 1) & 1] + oo);
      }
    }
#pragma unroll
    for (int tj = 0; tj < 4; ++tj) {
      bf16x8 a0 = lds_frag(Qt, tj * 16 + c, 16 * g);
      bf16x8 a1 = lds_frag(Qt, tj * 16 + c, 64 + 16 * g);
      f32x4 s0 = {0.f, 0.f, 0.f, 0.f}, s1 = {0.f, 0.f, 0.f, 0.f};
      s0 = __builtin_amdgcn_mfma_f32_16x16x32_bf16(a0, bm00, s0, 0, 0, 0);
      s0 = __builtin_amdgcn_mfma_f32_16x16x32_bf16(a1, bm01, s0, 0, 0, 0);
      s1 = __builtin_amdgcn_mfma_f32_16x16x32_bf16(a0, bm10, s1, 0, 0, 0);
      s1 = __builtin_amdgcn_mfma_f32_16x16x32_bf16(a1, bm11, s1, 0, 0, 0);
      float p0 = __expf(s0[0]), p1 = __expf(s0[1]), p2 = __expf(s0[2]), p3 = __expf(s0[3]);
      lc0 += (p0 + p1) + (p2 + p3);
      sP[wave][0][c][tj * 8 + 2 * g] = pk_bf16(p0, p1);
      sP[wave][0][c][tj * 8 + 2 * g + 1] = pk_bf16(p2, p3);
      float q0 = __expf(s1[0]), q1 = __expf(s1[1]), q2 = __expf(s1[2]), q3 = __expf(s1[3]);
      lc1 += (q0 + q1) + (q2 + q3);
      sP[wave][1][c][tj * 8 + 2 * g] = pk_bf16(q0, q1);
      sP[wave][1][c][tj * 8 + 2 * g + 1] = pk_bf16(q2, q3);
    }
#pragma unroll
    for (int ks = 0; ks < 2; ++ks) {
      bf16x8 ap0 = *(const bf16x8*)&sP[wave][0][c][ks * 16 + 4 * g];
      bf16x8 ap1 = *(const bf16x8*)&sP[wave][1][c][ks * 16 + 4 * g];
#pragma unroll
      for (int dt = 0; dt < 4; ++dt) {
        bf16x8 bv = lds_frag(Vt, dt * 16 + c, ks * 64 + 16 * g);
        o[0][dt] = __builtin_amdgcn_mfma_f32_16x16x32_bf16(ap0, bv, o[0][dt], 0, 0, 0);
        o[1][dt] = __builtin_amdgcn_mfma_f32_16x16x32_bf16(ap1, bv, o[1][dt], 0, 0, 0);
      }
    }
    __syncthreads();
  }

  lc0 += __shfl_xor(lc0, 16); lc0 += __shfl_xor(lc0, 32);
  lc1 += __shfl_xor(lc1, 16); lc1 += __shfl_xor(lc1, 32);
  int gi = chunk * 8 + bh;
  if (g == 0) {
    Gl[(size_t)gi * MPOS + i0 + c] = lc0;
    Gl[(size_t)gi * MPOS + i0 + 16 + c] = lc1;
  }
  float* gp = Gc + ((size_t)gi * MPOS + i0) * 64;
#pragma unroll
  for (int f = 0; f < 2; ++f)
#pragma unroll
    for (int dt = 0; dt < 4; ++dt)
#pragma unroll
      for (int r = 0; r < 4; ++r)
        gp[(size_t)(f * 16 + 4 * g + r) * 64 + dt * 16 + c] = o[f][dt][r];
}

// ---------------- combine col partials + map_out projection ----------------
__global__ __launch_bounds__(256) void k_map_out(const float* __restrict__ Gc,
                                                 const float* __restrict__ Gl,
                                                 const float* __restrict__ mow,
                                                 float* __restrict__ out2) {
  int m = blockIdx.x, b = blockIdx.y, t = threadIdx.x;
  __shared__ float sMA[256];
  __shared__ float sL[4];
  if (t < 4) {
    float l = 0.f;
#pragma unroll 4
    for (int ch = 0; ch < JSPLIT; ++ch) l += Gl[(size_t)(ch * 8 + b * 4 + t) * MPOS + m];
    sL[t] = 1.f / l;
  }
  __syncthreads();
  {
    int head = t & 3, dh = t >> 2;
    int bh = b * 4 + head;
    float a = 0.f;
#pragma unroll 4
    for (int ch = 0; ch < JSPLIT; ++ch)
      a += Gc[((size_t)(ch * 8 + bh) * MPOS + m) * 64 + dh];
    sMA[t] = a * sL[head];
  }
  __syncthreads();
  if (t < 64) {
    const float* wr = mow + t * 256;
    float acc = 0.f;
#pragma unroll 4
    for (int c = 0; c < 256; ++c) acc += wr[c] * sMA[c];
    out2[((size_t)b * 64 + t) * MPOS + m] = acc;
  }
}

// ---------------- pointwise out GEMM: [128,256] x dwo -> out1 --------------
__global__ __launch_bounds__(256) void k_pw_out(const float* __restrict__ dwo,
                                                const float* __restrict__ pw,
                                                float* __restrict__ out1) {
  __shared__ __align__(16) float sA[128][68];
  __shared__ __align__(16) float sW[128][68];
  int n0 = blockIdx.x * 64, co0 = blockIdx.y * 64, b = blockIdx.z;
  int t = threadIdx.x;
  int tx = t & 15, ty = t >> 4;
  float acc[4][4] = {};
  for (int kk = 0; kk < 2; ++kk) {
    __syncthreads();
#pragma unroll
    for (int r = 0; r < 32; ++r) {
      int e = r * 256 + t;
      int k = e >> 6, n = e & 63;
      sA[k][n] = dwo[((size_t)b * INNER + kk * 128 + k) * NPOS + n0 + n];
    }
#pragma unroll
    for (int r = 0; r < 32; ++r) {
      int e = r * 256 + t;
      int k = e & 127, co = e >> 7;
      sW[k][co] = pw[(size_t)(co0 + co) * INNER + kk * 128 + k];
    }
    __syncthreads();
#pragma unroll 4
    for (int k = 0; k < 128; ++k) {
      float4 a = *(const float4*)&sA[k][tx * 4];
      float4 wv = *(const float4*)&sW[k][ty * 4];
      float av[4] = {a.x, a.y, a.z, a.w};
      float wvv[4] = {wv.x, wv.y, wv.z, wv.w};
#pragma unroll
      for (int i = 0; i < 4; ++i)
#pragma unroll
        for (int j = 0; j < 4; ++j) acc[i][j] += wvv[i] * av[j];
    }
  }
#pragma unroll
  for (int i = 0; i < 4; ++i) {
    int co = co0 + ty * 4 + i;
#pragma unroll
    for (int j = 0; j < 4; ++j) {
      int n = n0 + tx * 4 + j;
      out1[((size_t)b * 128 + co) * NPOS + n] = acc[i][j];
    }
  }
}

extern "C" void kernel_launch(void* const* d_in, const int* in_sizes, int n_in,
                              void* d_out, int out_size, void* d_ws, size_t ws_size,
                              hipStream_t stream) {
  const float* feat = (const float*)d_in[0];
  const float* smap = (const float*)d_in[1];
  const float* fqv_dw = (const float*)d_in[2];
  const float* fqv_pw = (const float*)d_in[3];
  const float* fout_dw = (const float*)d_in[4];
  const float* fout_pw = (const float*)d_in[5];
  const float* mqv_w = (const float*)d_in[6];
  const float* mout_w = (const float*)d_in[7];

  float* out = (float*)d_out;
  float* out1 = out;                              // [2,128,24,24,24]
  float* out2 = out + (size_t)BB * 128 * NPOS;    // [2,64,8,8,8]

  const size_t QV = (size_t)BB * HEADS * NPOS * DH;   // 7,077,888
  const size_t MQV = (size_t)BB * HEADS * MPOS * DH;  // 262,144
  float* ws = (float*)d_ws;
  float* F = ws;                                       // fp32 attn row output
  unsigned short* fqb = (unsigned short*)(ws + QV);    // bf16 [bh][j][d]
  unsigned short* fvTb = fqb + QV;                     // bf16 [bh][d][j]
  unsigned short* mapqb = fvTb + QV;                   // bf16 [bh][i][d] (scaled)
  unsigned short* mapvTb = mapqb + MQV;                // bf16 [bh][d][i]
  float* Gc = (float*)(mapvTb + MQV);                  // [JSPLIT*8][512][64]
  float* Gl = Gc + (size_t)JSPLIT * 8 * MPOS * 64;     // [JSPLIT*8][512]
  float* dwo = (float*)fqb;  // reuse fqb+fvTb (28.3 MB) after col pass
  float* dwt = out1;         // depthwise-1 output lives in out1 region

  k_map_qv<<<dim3(BB * MPOS), dim3(512), 0, stream>>>(smap, mqv_w, mapqb, mapvTb);
  k_dw<<<dim3(BB * CH_FEAT), dim3(576), 0, stream>>>(feat, fqv_dw, dwt, CH_FEAT, 0);
  k_pw_qv<<<dim3(NPOS / 64, 8, BB), dim3(256), 0, stream>>>(dwt, fqv_pw, fqb, fvTb);
  k_attn_row<<<dim3(NPOS / 128, BB * HEADS), dim3(256), 0, stream>>>(fqb, mapqb, mapvTb, F);
  k_attn_col<<<dim3(MPOS / 128, BB * HEADS, JSPLIT), dim3(256), 0, stream>>>(fqb, fvTb, mapqb, Gc, Gl);
  k_map_out<<<dim3(MPOS, BB), dim3(256), 0, stream>>>(Gc, Gl, mout_w, out2);
  k_dw<<<dim3(BB * INNER), dim3(576), 0, stream>>>(F, fout_dw, dwo, INNER, 1);
  k_pw_out<<<dim3(NPOS / 64, 2, BB), dim3(256), 0, stream>>>(dwo, fout_pw, out1);
}

// Round 7
// 215.464 us; speedup vs baseline: 20.1528x; 1.2751x over previous
//
#include <hip/hip_runtime.h>

#define BB 2
#define CH_FEAT 128
#define HEADS 4
#define DH 64
#define INNER 256
#define NPOS 13824   // 24^3
#define MPOS 512     // 8^3
#define DSZ 24
#define JSPLIT 27    // col-pass j chunks
#define JCHUNK (NPOS / JSPLIT)  // 512

typedef __attribute__((ext_vector_type(8))) short bf16x8;
typedef __attribute__((ext_vector_type(4))) float f32x4;

__device__ inline unsigned short bf16_rn(float x) {
  unsigned u = __builtin_bit_cast(unsigned, x);
  u += 0x7FFF + ((u >> 16) & 1);
  return (unsigned short)(u >> 16);
}
__device__ inline unsigned pk_bf16(float a, float b) {
  return (unsigned)bf16_rn(a) | ((unsigned)bf16_rn(b) << 16);
}

// async global->LDS 16B (dest must be wave-uniform base + lane*16)
#define GL2LDS(g, l)                                                        \
  __builtin_amdgcn_global_load_lds(                                         \
      (const __attribute__((address_space(1))) void*)(g),                   \
      (__attribute__((address_space(3))) void*)(l), 16, 0, 0)

// swizzled read of a 16B fragment from a [rows][pitch B] LDS tile
__device__ inline bf16x8 lds_frag(const char* tile, int row, int colb) {
  return *(const bf16x8*)(tile + row * 128 + (colb ^ ((row & 7) << 4)));
}
__device__ inline bf16x8 lds_fragP(const char* tile, int row, int colb, int pitch) {
  return *(const bf16x8*)(tile + row * pitch + (colb ^ ((row & 7) << 4)));
}

// ---------------- map q/v projection -> bf16 mapq [bh][m][d], mapv^T [bh][d][m]
__global__ __launch_bounds__(512) void k_map_qv(const float* __restrict__ smap,
                                                const float* __restrict__ w,
                                                unsigned short* __restrict__ mapqb,
                                                unsigned short* __restrict__ mapvTb) {
  int bm = blockIdx.x;
  int b = bm >> 9, m = bm & 511;
  __shared__ float s[64];
  int t = threadIdx.x;
  if (t < 64) s[t] = smap[(size_t)(b * 64 + t) * MPOS + m];
  __syncthreads();
  const float* wr = w + t * 64;
  float acc = 0.f;
#pragma unroll
  for (int c = 0; c < 64; ++c) acc += wr[c] * s[c];
  int qv = t >> 8, c2 = t & 255, head = c2 & 3, dh = c2 >> 2;
  int bh = b * HEADS + head;
  if (qv == 0)
    mapqb[((size_t)bh * MPOS + m) * 64 + dh] = bf16_rn(acc * 0.125f);  // fold scale
  else
    mapvTb[((size_t)bh * 64 + dh) * MPOS + m] = bf16_rn(acc);
}

// ---------------- depthwise 3x3x3 SAME conv, register-rolling x-march ------
__global__ __launch_bounds__(576) void k_dw(const float* __restrict__ in,
                                            const float* __restrict__ w,
                                            float* __restrict__ out, int C, int remap) {
  int t = threadIdx.x;
  int bc = blockIdx.x;
  int c = bc & (C - 1), b = bc / C;
  int cm = remap ? ((c & 63) * 4 + (c >> 6)) : c;
  int y = t % 24, z = t / 24;
  const float* wr = w + cm * 27;
  const float* ip = in + (size_t)bc * NPOS;

  float wm[9][3];
  int off[9];
#pragma unroll
  for (int dz = 0; dz < 3; ++dz)
#pragma unroll
    for (int dy = 0; dy < 3; ++dy) {
      int r = dz * 3 + dy;
      int zz = z + dz - 1, yy = y + dy - 1;
      float m = ((unsigned)zz < 24u && (unsigned)yy < 24u) ? 1.f : 0.f;
      wm[r][0] = wr[dz * 9 + dy * 3 + 0] * m;
      wm[r][1] = wr[dz * 9 + dy * 3 + 1] * m;
      wm[r][2] = wr[dz * 9 + dy * 3 + 2] * m;
      int zc = min(max(zz, 0), 23), yc = min(max(yy, 0), 23);
      off[r] = (zc * 24 + yc) * 24;
    }

  float4 cur[9], nxt[9];
  float pl[9];
#pragma unroll
  for (int r = 0; r < 9; ++r) {
    pl[r] = 0.f;
    cur[r] = *(const float4*)(ip + off[r]);
    nxt[r] = *(const float4*)(ip + off[r] + 4);
  }

  float* op = out + ((size_t)b * C + cm) * NPOS + (z * 24 + y) * 24;
#pragma unroll
  for (int xc = 0; xc < 6; ++xc) {
    float4 acc;
    acc.x = acc.y = acc.z = acc.w = 0.f;
#pragma unroll
    for (int r = 0; r < 9; ++r) {
      float w0 = wm[r][0], w1 = wm[r][1], w2 = wm[r][2];
      float4 cu = cur[r];
      acc.x += w0 * pl[r] + w1 * cu.x + w2 * cu.y;
      acc.y += w0 * cu.x + w1 * cu.y + w2 * cu.z;
      acc.z += w0 * cu.y + w1 * cu.z + w2 * cu.w;
      acc.w += w0 * cu.z + w1 * cu.w + w2 * nxt[r].x;
    }
    *(float4*)(op + xc * 4) = acc;
    if (xc < 5) {
#pragma unroll
      for (int r = 0; r < 9; ++r) {
        pl[r] = cur[r].w;
        cur[r] = nxt[r];
        nxt[r] = (xc < 4) ? *(const float4*)(ip + off[r] + (xc + 2) * 4)
                          : make_float4(0.f, 0.f, 0.f, 0.f);
      }
    }
  }
}

// ---------------- transpose + bf16 convert: [b][C][N] f32 -> [b][N][C] bf16
__global__ __launch_bounds__(256) void k_tr(const float* __restrict__ in,
                                            unsigned short* __restrict__ outT, int C) {
  __shared__ float sT[64][65];
  int t = threadIdx.x;
  int n0 = blockIdx.x * 64, c0 = blockIdx.y * 64, b = blockIdx.z;
  {
    int r = t >> 2, seg = (t & 3) * 16;
    const float* ip = in + ((size_t)b * C + c0 + r) * NPOS + n0 + seg;
#pragma unroll
    for (int i = 0; i < 4; ++i) {
      float4 v = *(const float4*)(ip + i * 4);
      sT[r][seg + i * 4 + 0] = v.x;
      sT[r][seg + i * 4 + 1] = v.y;
      sT[r][seg + i * 4 + 2] = v.z;
      sT[r][seg + i * 4 + 3] = v.w;
    }
  }
  __syncthreads();
  int nr = t >> 2, cs = (t & 3) * 16;
  unsigned pkv[8];
#pragma unroll
  for (int i = 0; i < 8; ++i)
    pkv[i] = pk_bf16(sT[cs + 2 * i][nr], sT[cs + 2 * i + 1][nr]);
  unsigned short* op = outT + ((size_t)b * NPOS + n0 + nr) * C + c0 + cs;
  *(uint4*)(op) = *(uint4*)&pkv[0];
  *(uint4*)(op + 8) = *(uint4*)&pkv[4];
}

// ---------------- MFMA pointwise qv GEMM: fqv_pw x dwtT -> fq, fv^T --------
// block: co-tile ti=(qv,head) 64 dh x 128 n; A=weights (perm rows), B=dwtT
__global__ __launch_bounds__(256) void k_pwqv_m(const unsigned short* __restrict__ dwtT,
                                                const float* __restrict__ pw,
                                                unsigned short* __restrict__ fqb,
                                                unsigned short* __restrict__ fvTb) {
  __shared__ __align__(16) char sAB[49152];  // sW [0,16K) | sB [16K,48K) (dump aliases sB)
  char* sW = sAB;
  char* sB = sAB + 16384;
  int t = threadIdx.x, wave = t >> 6, lane = t & 63, g = lane >> 4, c = lane & 15;
  int n0 = blockIdx.x * 128, ti = blockIdx.y, b = blockIdx.z;
  int qv = ti >> 2, head = ti & 3, bh = b * 4 + head;

  {  // stage A: 64 dh x 128 k, permuted rows, swizzled, pitch 256B
    int r = t >> 2, ks = (t & 3) * 32;
    int co = qv * 256 + r * 4 + head;
    const float* wp = pw + (size_t)co * 128 + ks;
    unsigned pkv[16];
#pragma unroll
    for (int i = 0; i < 8; ++i) {
      float4 v = *(const float4*)(wp + i * 4);
      pkv[2 * i] = pk_bf16(v.x, v.y);
      pkv[2 * i + 1] = pk_bf16(v.z, v.w);
    }
#pragma unroll
    for (int u = 0; u < 4; ++u) {
      int colb = (ks * 2 + u * 16) ^ ((r & 7) << 4);
      *(uint4*)(sW + r * 256 + colb) = *(uint4*)&pkv[u * 4];
    }
  }
  const char* Bg = (const char*)(dwtT + ((size_t)b * NPOS + n0) * 128);
#pragma unroll
  for (int p = 0; p < 8; ++p) {  // stage B: 128 n x 128 k, pitch 256B
    int oo = p * 4096 + t * 16;
    int row = oo >> 8, col = (oo & 255) ^ (((oo >> 8) & 7) << 4);
    GL2LDS(Bg + (size_t)row * 256 + col, sB + oo);
  }
  __syncthreads();

  f32x4 acc[4][2];
#pragma unroll
  for (int ct = 0; ct < 4; ++ct)
#pragma unroll
    for (int jf = 0; jf < 2; ++jf) acc[ct][jf] = (f32x4){0.f, 0.f, 0.f, 0.f};
  int nw = wave * 32;
#pragma unroll
  for (int kc = 0; kc < 4; ++kc) {
    bf16x8 bq[2];
#pragma unroll
    for (int jf = 0; jf < 2; ++jf)
      bq[jf] = lds_fragP(sB, nw + jf * 16 + c, kc * 64 + g * 16, 256);
#pragma unroll
    for (int ct = 0; ct < 4; ++ct) {
      bf16x8 a = lds_fragP(sW, ct * 16 + c, kc * 64 + g * 16, 256);
#pragma unroll
      for (int jf = 0; jf < 2; ++jf)
        acc[ct][jf] = __builtin_amdgcn_mfma_f32_16x16x32_bf16(a, bq[jf], acc[ct][jf], 0, 0, 0);
    }
  }
  __syncthreads();

  // dump [n 128][dh 64] bf16, pitch 144B (bank-spread)
  char* dmp = sB;
#pragma unroll
  for (int ct = 0; ct < 4; ++ct)
#pragma unroll
    for (int jf = 0; jf < 2; ++jf) {
      int n = nw + jf * 16 + c;
      uint2 wv;
      wv.x = pk_bf16(acc[ct][jf][0], acc[ct][jf][1]);
      wv.y = pk_bf16(acc[ct][jf][2], acc[ct][jf][3]);
      *(uint2*)(dmp + n * 144 + (ct * 16 + 4 * g) * 2) = wv;
    }
  __syncthreads();

  if (qv == 0) {  // fq[bh][n][dh]: coalesced 64B row writes
    int nr = t >> 1, seg = t & 1;
    const char* src = dmp + nr * 144 + seg * 64;
    unsigned short* dst = fqb + ((size_t)bh * NPOS + n0 + nr) * 64 + seg * 32;
#pragma unroll
    for (int i = 0; i < 4; ++i)
      *(uint4*)(dst + i * 8) = *(const uint4*)(src + i * 16);
  } else {  // fvT[bh][dh][n]: transpose read from dump
#pragma unroll
    for (int it = 0; it < 2; ++it) {
      int idx = it * 256 + t;
      int dh = idx >> 3, nseg = (idx & 7) * 16;
      unsigned pkv[8];
#pragma unroll
      for (int i = 0; i < 8; ++i) {
        unsigned short lo = *(const unsigned short*)(dmp + (nseg + 2 * i) * 144 + dh * 2);
        unsigned short hi = *(const unsigned short*)(dmp + (nseg + 2 * i + 1) * 144 + dh * 2);
        pkv[i] = (unsigned)lo | ((unsigned)hi << 16);
      }
      unsigned short* dst = fvTb + ((size_t)bh * 64 + dh) * NPOS + n0 + nseg;
      *(uint4*)(dst) = *(uint4*)&pkv[0];
      *(uint4*)(dst + 8) = *(uint4*)&pkv[4];
    }
  }
}

// ---------------- MFMA pointwise out GEMM: fout_pw x dwoT -> out1 (fp32) ---
__global__ __launch_bounds__(256) void k_pwout_m(const unsigned short* __restrict__ dwoT,
                                                 const float* __restrict__ pw,
                                                 float* __restrict__ out1) {
  __shared__ __align__(16) char sW[32768];  // [64 co][512B k=256]
  __shared__ __align__(16) char sB[32768];  // [128 n][256B k-half]
  int t = threadIdx.x, wave = t >> 6, lane = t & 63, g = lane >> 4, c = lane & 15;
  int n0 = blockIdx.x * 128, ti = blockIdx.y, b = blockIdx.z;

  {  // stage A full k=256
    int r = t >> 2, ks = (t & 3) * 64;
    const float* wp = pw + (size_t)(ti * 64 + r) * 256 + ks;
    unsigned pkv[32];
#pragma unroll
    for (int i = 0; i < 16; ++i) {
      float4 v = *(const float4*)(wp + i * 4);
      pkv[2 * i] = pk_bf16(v.x, v.y);
      pkv[2 * i + 1] = pk_bf16(v.z, v.w);
    }
#pragma unroll
    for (int u = 0; u < 8; ++u) {
      int colb = (ks * 2 + u * 16) ^ ((r & 7) << 4);
      *(uint4*)(sW + r * 512 + colb) = *(uint4*)&pkv[u * 4];
    }
  }

  f32x4 acc[4][2];
#pragma unroll
  for (int ct = 0; ct < 4; ++ct)
#pragma unroll
    for (int jf = 0; jf < 2; ++jf) acc[ct][jf] = (f32x4){0.f, 0.f, 0.f, 0.f};
  int nw = wave * 32;
  const char* Bg = (const char*)(dwoT + ((size_t)b * NPOS + n0) * 256);

  for (int kh = 0; kh < 2; ++kh) {
#pragma unroll
    for (int p = 0; p < 8; ++p) {
      int oo = p * 4096 + t * 16;
      int row = oo >> 8, col = (oo & 255) ^ (((oo >> 8) & 7) << 4);
      GL2LDS(Bg + (size_t)row * 512 + kh * 256 + col, sB + oo);
    }
    __syncthreads();
#pragma unroll
    for (int kc = 0; kc < 4; ++kc) {
      bf16x8 bq[2];
#pragma unroll
      for (int jf = 0; jf < 2; ++jf)
        bq[jf] = lds_fragP(sB, nw + jf * 16 + c, kc * 64 + g * 16, 256);
#pragma unroll
      for (int ct = 0; ct < 4; ++ct) {
        bf16x8 a = lds_fragP(sW, ct * 16 + c, (kh * 4 + kc) * 64 + g * 16, 512);
#pragma unroll
        for (int jf = 0; jf < 2; ++jf)
          acc[ct][jf] = __builtin_amdgcn_mfma_f32_16x16x32_bf16(a, bq[jf], acc[ct][jf], 0, 0, 0);
      }
    }
    __syncthreads();
  }
#pragma unroll
  for (int ct = 0; ct < 4; ++ct)
#pragma unroll
    for (int jf = 0; jf < 2; ++jf) {
      int n = n0 + nw + jf * 16 + c;
#pragma unroll
      for (int r = 0; r < 4; ++r) {
        int co = ti * 64 + ct * 16 + 4 * g + r;
        out1[((size_t)b * 128 + co) * NPOS + n] = acc[ct][jf][r];
      }
    }
}

// ---------------- MFMA attention row pass (LDS-staged, double-buffered) ----
__global__ __launch_bounds__(256) void k_attn_row(const unsigned short* __restrict__ fqb,
                                                  const unsigned short* __restrict__ mapqb,
                                                  const unsigned short* __restrict__ mapvTb,
                                                  float* __restrict__ F) {
  __shared__ __align__(16) char sK[2][8192];
  __shared__ __align__(16) char sV[2][8192];
  __shared__ __align__(16) unsigned sP[4][2][16][36];
  __shared__ float sL[4][2][16];
  int t = threadIdx.x, wave = t >> 6, lane = t & 63, g = lane >> 4, c = lane & 15;
  int bh = blockIdx.y;
  int j0 = blockIdx.x * 128 + wave * 32;

  const char* Kg = (const char*)(mapqb + (size_t)bh * MPOS * 64);
  const char* Vg = (const char*)(mapvTb + (size_t)bh * 64 * MPOS);

  const unsigned short* fqp = fqb + ((size_t)bh * NPOS + j0 + c) * 64 + 8 * g;
  bf16x8 bq00 = *(const bf16x8*)(fqp);
  bf16x8 bq01 = *(const bf16x8*)(fqp + 32);
  bf16x8 bq10 = *(const bf16x8*)(fqp + 16 * 64);
  bf16x8 bq11 = *(const bf16x8*)(fqp + 16 * 64 + 32);

  f32x4 o[2][4];
#pragma unroll
  for (int jf = 0; jf < 2; ++jf)
#pragma unroll
    for (int dt = 0; dt < 4; ++dt) o[jf][dt] = (f32x4){0.f, 0.f, 0.f, 0.f};
  float ls0 = 0.f, ls1 = 0.f;

#pragma unroll
  for (int p = 0; p < 2; ++p) {
    int oo = p * 4096 + t * 16;
    int row = oo >> 7, col = (oo & 127) ^ (((oo >> 7) & 7) << 4);
    GL2LDS(Kg + (size_t)row * 128 + col, sK[0] + oo);
    GL2LDS(Vg + (size_t)row * 1024 + col, sV[0] + oo);
  }
  __syncthreads();

  for (int ic = 0; ic < 8; ++ic) {
    const char* Kt = sK[ic & 1];
    const char* Vt = sV[ic & 1];
    if (ic < 7) {
      int ibase = (ic + 1) * 64;
#pragma unroll
      for (int p = 0; p < 2; ++p) {
        int oo = p * 4096 + t * 16;
        int row = oo >> 7, col = (oo & 127) ^ (((oo >> 7) & 7) << 4);
        GL2LDS(Kg + (size_t)(ibase + row) * 128 + col, sK[(ic + 1) & 1] + oo);
        GL2LDS(Vg + (size_t)row * 1024 + ibase * 2 + col, sV[(ic + 1) & 1] + oo);
      }
    }
#pragma unroll
    for (int ti = 0; ti < 4; ++ti) {
      bf16x8 a0 = lds_frag(Kt, ti * 16 + c, 16 * g);
      bf16x8 a1 = lds_frag(Kt, ti * 16 + c, 64 + 16 * g);
      f32x4 s0 = {0.f, 0.f, 0.f, 0.f}, s1 = {0.f, 0.f, 0.f, 0.f};
      s0 = __builtin_amdgcn_mfma_f32_16x16x32_bf16(a0, bq00, s0, 0, 0, 0);
      s0 = __builtin_amdgcn_mfma_f32_16x16x32_bf16(a1, bq01, s0, 0, 0, 0);
      s1 = __builtin_amdgcn_mfma_f32_16x16x32_bf16(a0, bq10, s1, 0, 0, 0);
      s1 = __builtin_amdgcn_mfma_f32_16x16x32_bf16(a1, bq11, s1, 0, 0, 0);
      float p0 = __expf(s0[0]), p1 = __expf(s0[1]), p2 = __expf(s0[2]), p3 = __expf(s0[3]);
      ls0 += (p0 + p1) + (p2 + p3);
      sP[wave][0][c][ti * 8 + 2 * g] = pk_bf16(p0, p1);
      sP[wave][0][c][ti * 8 + 2 * g + 1] = pk_bf16(p2, p3);
      float q0 = __expf(s1[0]), q1 = __expf(s1[1]), q2 = __expf(s1[2]), q3 = __expf(s1[3]);
      ls1 += (q0 + q1) + (q2 + q3);
      sP[wave][1][c][ti * 8 + 2 * g] = pk_bf16(q0, q1);
      sP[wave][1][c][ti * 8 + 2 * g + 1] = pk_bf16(q2, q3);
    }
#pragma unroll
    for (int ks = 0; ks < 2; ++ks) {
      bf16x8 ap0 = *(const bf16x8*)&sP[wave][0][c][ks * 16 + 4 * g];
      bf16x8 ap1 = *(const bf16x8*)&sP[wave][1][c][ks * 16 + 4 * g];
#pragma unroll
      for (int dt = 0; dt < 4; ++dt) {
        bf16x8 bv = lds_frag(Vt, dt * 16 + c, ks * 64 + 16 * g);
        o[0][dt] = __builtin_amdgcn_mfma_f32_16x16x32_bf16(ap0, bv, o[0][dt], 0, 0, 0);
        o[1][dt] = __builtin_amdgcn_mfma_f32_16x16x32_bf16(ap1, bv, o[1][dt], 0, 0, 0);
      }
    }
    __syncthreads();
  }

  ls0 += __shfl_xor(ls0, 16); ls0 += __shfl_xor(ls0, 32);
  ls1 += __shfl_xor(ls1, 16); ls1 += __shfl_xor(ls1, 32);
  if (g == 0) { sL[wave][0][c] = 1.f / ls0; sL[wave][1][c] = 1.f / ls1; }
  int b = bh >> 2, head = bh & 3;
#pragma unroll
  for (int jf = 0; jf < 2; ++jf) {
    float rl0 = sL[wave][jf][4 * g + 0], rl1 = sL[wave][jf][4 * g + 1];
    float rl2 = sL[wave][jf][4 * g + 2], rl3 = sL[wave][jf][4 * g + 3];
#pragma unroll
    for (int dt = 0; dt < 4; ++dt) {
      float4 v = make_float4(o[jf][dt][0] * rl0, o[jf][dt][1] * rl1,
                             o[jf][dt][2] * rl2, o[jf][dt][3] * rl3);
      *(float4*)(F + ((size_t)b * INNER + head * 64 + dt * 16 + c) * NPOS +
                 j0 + jf * 16 + 4 * g) = v;
    }
  }
}

// ---------------- MFMA attention col pass (LDS-staged, j-chunked) ----------
__global__ __launch_bounds__(256) void k_attn_col(const unsigned short* __restrict__ fqb,
                                                  const unsigned short* __restrict__ fvTb,
                                                  const unsigned short* __restrict__ mapqb,
                                                  float* __restrict__ Gc,
                                                  float* __restrict__ Gl) {
  __shared__ __align__(16) char sQ[2][8192];
  __shared__ __align__(16) char sV[2][8192];
  __shared__ __align__(16) unsigned sP[4][2][16][36];
  int t = threadIdx.x, wave = t >> 6, lane = t & 63, g = lane >> 4, c = lane & 15;
  int bh = blockIdx.y, chunk = blockIdx.z;
  int i0 = blockIdx.x * 128 + wave * 32;
  int jb = chunk * JCHUNK;

  const char* Qg = (const char*)(fqb + (size_t)bh * NPOS * 64);
  const char* Vg = (const char*)(fvTb + (size_t)bh * 64 * NPOS);

  const unsigned short* kp = mapqb + ((size_t)bh * MPOS + i0 + c) * 64 + 8 * g;
  bf16x8 bm00 = *(const bf16x8*)(kp);
  bf16x8 bm01 = *(const bf16x8*)(kp + 32);
  bf16x8 bm10 = *(const bf16x8*)(kp + 16 * 64);
  bf16x8 bm11 = *(const bf16x8*)(kp + 16 * 64 + 32);

  f32x4 o[2][4];
#pragma unroll
  for (int f = 0; f < 2; ++f)
#pragma unroll
    for (int dt = 0; dt < 4; ++dt) o[f][dt] = (f32x4){0.f, 0.f, 0.f, 0.f};
  float lc0 = 0.f, lc1 = 0.f;

#pragma unroll
  for (int p = 0; p < 2; ++p) {
    int oo = p * 4096 + t * 16;
    int row = oo >> 7, col = (oo & 127) ^ (((oo >> 7) & 7) << 4);
    GL2LDS(Qg + (size_t)(jb + row) * 128 + col, sQ[0] + oo);
    GL2LDS(Vg + (size_t)row * (NPOS * 2) + jb * 2 + col, sV[0] + oo);
  }
  __syncthreads();

  for (int jc = 0; jc < JCHUNK / 64; ++jc) {
    const char* Qt = sQ[jc & 1];
    const char* Vt = sV[jc & 1];
    if (jc < JCHUNK / 64 - 1) {
      int jbase = jb + (jc + 1) * 64;
#pragma unroll
      for (int p = 0; p < 2; ++p) {
        int oo = p * 4096 + t * 16;
        int row = oo >> 7, col = (oo & 127) ^ (((oo >> 7) & 7) << 4);
        GL2LDS(Qg + (size_t)(jbase + row) * 128 + col, sQ[(jc + 1) & 1] + oo);
        GL2LDS(Vg + (size_t)row * (NPOS * 2) + jbase * 2 + col, sV[(jc + 1) & 1] + oo);
      }
    }
#pragma unroll
    for (int tj = 0; tj < 4; ++tj) {
      bf16x8 a0 = lds_frag(Qt, tj * 16 + c, 16 * g);
      bf16x8 a1 = lds_frag(Qt, tj * 16 + c, 64 + 16 * g);
      f32x4 s0 = {0.f, 0.f, 0.f, 0.f}, s1 = {0.f, 0.f, 0.f, 0.f};
      s0 = __builtin_amdgcn_mfma_f32_16x16x32_bf16(a0, bm00, s0, 0, 0, 0);
      s0 = __builtin_amdgcn_mfma_f32_16x16x32_bf16(a1, bm01, s0, 0, 0, 0);
      s1 = __builtin_amdgcn_mfma_f32_16x16x32_bf16(a0, bm10, s1, 0, 0, 0);
      s1 = __builtin_amdgcn_mfma_f32_16x16x32_bf16(a1, bm11, s1, 0, 0, 0);
      float p0 = __expf(s0[0]), p1 = __expf(s0[1]), p2 = __expf(s0[2]), p3 = __expf(s0[3]);
      lc0 += (p0 + p1) + (p2 + p3);
      sP[wave][0][c][tj * 8 + 2 * g] = pk_bf16(p0, p1);
      sP[wave][0][c][tj * 8 + 2 * g + 1] = pk_bf16(p2, p3);
      float q0 = __expf(s1[0]), q1 = __expf(s1[1]), q2 = __expf(s1[2]), q3 = __expf(s1[3]);
      lc1 += (q0 + q1) + (q2 + q3);
      sP[wave][1][c][tj * 8 + 2 * g] = pk_bf16(q0, q1);
      sP[wave][1][c][tj * 8 + 2 * g + 1] = pk_bf16(q2, q3);
    }
#pragma unroll
    for (int ks = 0; ks < 2; ++ks) {
      bf16x8 ap0 = *(const bf16x8*)&sP[wave][0][c][ks * 16 + 4 * g];
      bf16x8 ap1 = *(const bf16x8*)&sP[wave][1][c][ks * 16 + 4 * g];
#pragma unroll
      for (int dt = 0; dt < 4; ++dt) {
        bf16x8 bv = lds_frag(Vt, dt * 16 + c, ks * 64 + 16 * g);
        o[0][dt] = __builtin_amdgcn_mfma_f32_16x16x32_bf16(ap0, bv, o[0][dt], 0, 0, 0);
        o[1][dt] = __builtin_amdgcn_mfma_f32_16x16x32_bf16(ap1, bv, o[1][dt], 0, 0, 0);
      }
    }
    __syncthreads();
  }

  lc0 += __shfl_xor(lc0, 16); lc0 += __shfl_xor(lc0, 32);
  lc1 += __shfl_xor(lc1, 16); lc1 += __shfl_xor(lc1, 32);
  int gi = chunk * 8 + bh;
  if (g == 0) {
    Gl[(size_t)gi * MPOS + i0 + c] = lc0;
    Gl[(size_t)gi * MPOS + i0 + 16 + c] = lc1;
  }
  float* gp = Gc + ((size_t)gi * MPOS + i0) * 64;
#pragma unroll
  for (int f = 0; f < 2; ++f)
#pragma unroll
    for (int dt = 0; dt < 4; ++dt)
#pragma unroll
      for (int r = 0; r < 4; ++r)
        gp[(size_t)(f * 16 + 4 * g + r) * 64 + dt * 16 + c] = o[f][dt][r];
}

// ---------------- combine col partials + map_out projection ----------------
__global__ __launch_bounds__(256) void k_map_out(const float* __restrict__ Gc,
                                                 const float* __restrict__ Gl,
                                                 const float* __restrict__ mow,
                                                 float* __restrict__ out2) {
  int m = blockIdx.x, b = blockIdx.y, t = threadIdx.x;
  __shared__ float sMA[256];
  __shared__ float sL[4];
  if (t < 4) {
    float l = 0.f;
#pragma unroll 4
    for (int ch = 0; ch < JSPLIT; ++ch) l += Gl[(size_t)(ch * 8 + b * 4 + t) * MPOS + m];
    sL[t] = 1.f / l;
  }
  __syncthreads();
  {
    int head = t & 3, dh = t >> 2;
    int bh = b * 4 + head;
    float a = 0.f;
#pragma unroll 4
    for (int ch = 0; ch < JSPLIT; ++ch)
      a += Gc[((size_t)(ch * 8 + bh) * MPOS + m) * 64 + dh];
    sMA[t] = a * sL[head];
  }
  __syncthreads();
  if (t < 64) {
    const float* wr = mow + t * 256;
    float acc = 0.f;
#pragma unroll 4
    for (int c = 0; c < 256; ++c) acc += wr[c] * sMA[c];
    out2[((size_t)b * 64 + t) * MPOS + m] = acc;
  }
}

extern "C" void kernel_launch(void* const* d_in, const int* in_sizes, int n_in,
                              void* d_out, int out_size, void* d_ws, size_t ws_size,
                              hipStream_t stream) {
  const float* feat = (const float*)d_in[0];
  const float* smap = (const float*)d_in[1];
  const float* fqv_dw = (const float*)d_in[2];
  const float* fqv_pw = (const float*)d_in[3];
  const float* fout_dw = (const float*)d_in[4];
  const float* fout_pw = (const float*)d_in[5];
  const float* mqv_w = (const float*)d_in[6];
  const float* mout_w = (const float*)d_in[7];

  float* out = (float*)d_out;
  float* out1 = out;                              // [2,128,24,24,24]
  float* out2 = out + (size_t)BB * 128 * NPOS;    // [2,64,8,8,8]

  const size_t QV = (size_t)BB * HEADS * NPOS * DH;   // 7,077,888
  const size_t MQV = (size_t)BB * HEADS * MPOS * DH;  // 262,144
  float* ws = (float*)d_ws;
  float* F = ws;                                       // fp32 attn row output
  unsigned short* fqb = (unsigned short*)(ws + QV);    // bf16 [bh][j][d]
  unsigned short* fvTb = fqb + QV;                     // bf16 [bh][d][j]
  unsigned short* mapqb = fvTb + QV;                   // bf16 [bh][i][d] (scaled)
  unsigned short* mapvTb = mapqb + MQV;                // bf16 [bh][d][i]
  float* Gc = (float*)(mapvTb + MQV);                  // [JSPLIT*8][512][64]
  float* Gl = Gc + (size_t)JSPLIT * 8 * MPOS * 64;     // [JSPLIT*8][512]

  // lifetime-disjoint aliases
  float* dwt = out1;                    // dw1 output (fp32), dead after tr1+pw_out overwrite
  unsigned short* dwtT = (unsigned short*)Gc;  // [b][N][128] bf16; dead before attn_col
  float* dwt2 = (float*)fqb;            // dw2 output fp32 [b][256][N]; fq/fv dead after attn_col
  unsigned short* dwoT = (unsigned short*)F;   // [b][N][256] bf16; F dead after dw2

  k_map_qv<<<dim3(BB * MPOS), dim3(512), 0, stream>>>(smap, mqv_w, mapqb, mapvTb);
  k_dw<<<dim3(BB * CH_FEAT), dim3(576), 0, stream>>>(feat, fqv_dw, dwt, CH_FEAT, 0);
  k_tr<<<dim3(NPOS / 64, CH_FEAT / 64, BB), dim3(256), 0, stream>>>(dwt, dwtT, CH_FEAT);
  k_pwqv_m<<<dim3(NPOS / 128, 8, BB), dim3(256), 0, stream>>>(dwtT, fqv_pw, fqb, fvTb);
  k_attn_row<<<dim3(NPOS / 128, BB * HEADS), dim3(256), 0, stream>>>(fqb, mapqb, mapvTb, F);
  k_attn_col<<<dim3(MPOS / 128, BB * HEADS, JSPLIT), dim3(256), 0, stream>>>(fqb, fvTb, mapqb, Gc, Gl);
  k_map_out<<<dim3(MPOS, BB), dim3(256), 0, stream>>>(Gc, Gl, mout_w, out2);
  k_dw<<<dim3(BB * INNER), dim3(576), 0, stream>>>(F, fout_dw, dwt2, INNER, 1);
  k_tr<<<dim3(NPOS / 64, INNER / 64, BB), dim3(256), 0, stream>>>(dwt2, dwoT, INNER);
  k_pwout_m<<<dim3(NPOS / 128, 2, BB), dim3(256), 0, stream>>>(dwoT, fout_pw, out1);
}

// Round 8
// 205.772 us; speedup vs baseline: 21.1020x; 1.0471x over previous
//
#include <hip/hip_runtime.h>

#define BB 2
#define CH_FEAT 128
#define HEADS 4
#define DH 64
#define INNER 256
#define NPOS 13824   // 24^3
#define MPOS 512     // 8^3
#define DSZ 24
#define JSPLIT 12    // col-pass j chunks
#define JCHUNK (NPOS / JSPLIT)  // 1152

typedef __attribute__((ext_vector_type(8))) short bf16x8;
typedef __attribute__((ext_vector_type(4))) float f32x4;

__device__ inline unsigned short bf16_rn(float x) {
  unsigned u = __builtin_bit_cast(unsigned, x);
  u += 0x7FFF + ((u >> 16) & 1);
  return (unsigned short)(u >> 16);
}
__device__ inline unsigned pk_bf16(float a, float b) {
  return (unsigned)bf16_rn(a) | ((unsigned)bf16_rn(b) << 16);
}
__device__ inline float4 ld_bf4(const unsigned short* p) {  // 4 bf16 -> float4
  uint2 u = *(const uint2*)p;
  float4 f;
  f.x = __builtin_bit_cast(float, (u.x & 0xFFFFu) << 16);
  f.y = __builtin_bit_cast(float, u.x & 0xFFFF0000u);
  f.z = __builtin_bit_cast(float, (u.y & 0xFFFFu) << 16);
  f.w = __builtin_bit_cast(float, u.y & 0xFFFF0000u);
  return f;
}
__device__ inline void st_bf4(unsigned short* p, float4 v) {
  uint2 u;
  u.x = pk_bf16(v.x, v.y);
  u.y = pk_bf16(v.z, v.w);
  *(uint2*)p = u;
}

// async global->LDS 16B (dest must be wave-uniform base + lane*16)
#define GL2LDS(g, l)                                                        \
  __builtin_amdgcn_global_load_lds(                                         \
      (const __attribute__((address_space(1))) void*)(g),                   \
      (__attribute__((address_space(3))) void*)(l), 16, 0, 0)

// swizzled read of a 16B fragment from a [rows][pitch B] LDS tile
__device__ inline bf16x8 lds_frag(const char* tile, int row, int colb) {
  return *(const bf16x8*)(tile + row * 128 + (colb ^ ((row & 7) << 4)));
}
__device__ inline bf16x8 lds_fragP(const char* tile, int row, int colb, int pitch) {
  return *(const bf16x8*)(tile + row * pitch + (colb ^ ((row & 7) << 4)));
}

// ---------------- map q/v projection -> bf16 mapq [bh][m][d], mapv^T [bh][d][m]
__global__ __launch_bounds__(512) void k_map_qv(const float* __restrict__ smap,
                                                const float* __restrict__ w,
                                                unsigned short* __restrict__ mapqb,
                                                unsigned short* __restrict__ mapvTb) {
  int bm = blockIdx.x;
  int b = bm >> 9, m = bm & 511;
  __shared__ float s[64];
  int t = threadIdx.x;
  if (t < 64) s[t] = smap[(size_t)(b * 64 + t) * MPOS + m];
  __syncthreads();
  const float* wr = w + t * 64;
  float acc = 0.f;
#pragma unroll
  for (int c = 0; c < 64; ++c) acc += wr[c] * s[c];
  int qv = t >> 8, c2 = t & 255, head = c2 & 3, dh = c2 >> 2;
  int bh = b * HEADS + head;
  if (qv == 0)
    mapqb[((size_t)bh * MPOS + m) * 64 + dh] = bf16_rn(acc * 0.125f);  // fold scale
  else
    mapvTb[((size_t)bh * 64 + dh) * MPOS + m] = bf16_rn(acc);
}

// ---------------- depthwise 3x3x3 SAME conv, f32 in -> bf16 out ------------
__global__ __launch_bounds__(576) void k_dw_f2b(const float* __restrict__ in,
                                                const float* __restrict__ w,
                                                unsigned short* __restrict__ out, int C) {
  int t = threadIdx.x;
  int bc = blockIdx.x;
  int c = bc & (C - 1), b = bc / C;
  int y = t % 24, z = t / 24;
  const float* wr = w + c * 27;
  const float* ip = in + (size_t)bc * NPOS;

  float wm[9][3];
  int off[9];
#pragma unroll
  for (int dz = 0; dz < 3; ++dz)
#pragma unroll
    for (int dy = 0; dy < 3; ++dy) {
      int r = dz * 3 + dy;
      int zz = z + dz - 1, yy = y + dy - 1;
      float m = ((unsigned)zz < 24u && (unsigned)yy < 24u) ? 1.f : 0.f;
      wm[r][0] = wr[dz * 9 + dy * 3 + 0] * m;
      wm[r][1] = wr[dz * 9 + dy * 3 + 1] * m;
      wm[r][2] = wr[dz * 9 + dy * 3 + 2] * m;
      int zc = min(max(zz, 0), 23), yc = min(max(yy, 0), 23);
      off[r] = (zc * 24 + yc) * 24;
    }

  float4 cur[9], nxt[9];
  float pl[9];
#pragma unroll
  for (int r = 0; r < 9; ++r) {
    pl[r] = 0.f;
    cur[r] = *(const float4*)(ip + off[r]);
    nxt[r] = *(const float4*)(ip + off[r] + 4);
  }

  unsigned short* op = out + ((size_t)b * C + c) * NPOS + (z * 24 + y) * 24;
#pragma unroll
  for (int xc = 0; xc < 6; ++xc) {
    float4 acc;
    acc.x = acc.y = acc.z = acc.w = 0.f;
#pragma unroll
    for (int r = 0; r < 9; ++r) {
      float w0 = wm[r][0], w1 = wm[r][1], w2 = wm[r][2];
      float4 cu = cur[r];
      acc.x += w0 * pl[r] + w1 * cu.x + w2 * cu.y;
      acc.y += w0 * cu.x + w1 * cu.y + w2 * cu.z;
      acc.z += w0 * cu.y + w1 * cu.z + w2 * cu.w;
      acc.w += w0 * cu.z + w1 * cu.w + w2 * nxt[r].x;
    }
    st_bf4(op + xc * 4, acc);
    if (xc < 5) {
#pragma unroll
      for (int r = 0; r < 9; ++r) {
        pl[r] = cur[r].w;
        cur[r] = nxt[r];
        nxt[r] = (xc < 4) ? *(const float4*)(ip + off[r] + (xc + 2) * 4)
                          : make_float4(0.f, 0.f, 0.f, 0.f);
      }
    }
  }
}

// ---------------- depthwise 3x3x3 SAME conv, bf16 in -> bf16 out, remap ----
__global__ __launch_bounds__(576) void k_dw_b2b(const unsigned short* __restrict__ in,
                                                const float* __restrict__ w,
                                                unsigned short* __restrict__ out, int C) {
  int t = threadIdx.x;
  int bc = blockIdx.x;
  int c = bc & (C - 1), b = bc / C;
  int cm = (c & 63) * 4 + (c >> 6);  // storage head*64+d -> merged d*4+head
  int y = t % 24, z = t / 24;
  const float* wr = w + cm * 27;
  const unsigned short* ip = in + (size_t)bc * NPOS;

  float wm[9][3];
  int off[9];
#pragma unroll
  for (int dz = 0; dz < 3; ++dz)
#pragma unroll
    for (int dy = 0; dy < 3; ++dy) {
      int r = dz * 3 + dy;
      int zz = z + dz - 1, yy = y + dy - 1;
      float m = ((unsigned)zz < 24u && (unsigned)yy < 24u) ? 1.f : 0.f;
      wm[r][0] = wr[dz * 9 + dy * 3 + 0] * m;
      wm[r][1] = wr[dz * 9 + dy * 3 + 1] * m;
      wm[r][2] = wr[dz * 9 + dy * 3 + 2] * m;
      int zc = min(max(zz, 0), 23), yc = min(max(yy, 0), 23);
      off[r] = (zc * 24 + yc) * 24;
    }

  float4 cur[9], nxt[9];
  float pl[9];
#pragma unroll
  for (int r = 0; r < 9; ++r) {
    pl[r] = 0.f;
    cur[r] = ld_bf4(ip + off[r]);
    nxt[r] = ld_bf4(ip + off[r] + 4);
  }

  unsigned short* op = out + ((size_t)b * C + cm) * NPOS + (z * 24 + y) * 24;
#pragma unroll
  for (int xc = 0; xc < 6; ++xc) {
    float4 acc;
    acc.x = acc.y = acc.z = acc.w = 0.f;
#pragma unroll
    for (int r = 0; r < 9; ++r) {
      float w0 = wm[r][0], w1 = wm[r][1], w2 = wm[r][2];
      float4 cu = cur[r];
      acc.x += w0 * pl[r] + w1 * cu.x + w2 * cu.y;
      acc.y += w0 * cu.x + w1 * cu.y + w2 * cu.z;
      acc.z += w0 * cu.y + w1 * cu.z + w2 * cu.w;
      acc.w += w0 * cu.z + w1 * cu.w + w2 * nxt[r].x;
    }
    st_bf4(op + xc * 4, acc);
    if (xc < 5) {
#pragma unroll
      for (int r = 0; r < 9; ++r) {
        pl[r] = cur[r].w;
        cur[r] = nxt[r];
        nxt[r] = (xc < 4) ? ld_bf4(ip + off[r] + (xc + 2) * 4)
                          : make_float4(0.f, 0.f, 0.f, 0.f);
      }
    }
  }
}

// ---------------- transpose bf16: [b][C][N] -> [b][N][C] -------------------
__global__ __launch_bounds__(256) void k_trb(const unsigned short* __restrict__ in,
                                             unsigned short* __restrict__ outT, int C) {
  __shared__ unsigned sT[64][33];  // [c][n-pair]
  int t = threadIdx.x;
  int n0 = blockIdx.x * 64, c0 = blockIdx.y * 64, b = blockIdx.z;
  {
    int r = t >> 2, s8 = (t & 3) * 8;
    const unsigned short* ip = in + ((size_t)b * C + c0 + r) * NPOS + n0 + s8 * 2;
    uint4 a = *(const uint4*)(ip);
    uint4 b2 = *(const uint4*)(ip + 8);
    sT[r][s8 + 0] = a.x; sT[r][s8 + 1] = a.y; sT[r][s8 + 2] = a.z; sT[r][s8 + 3] = a.w;
    sT[r][s8 + 4] = b2.x; sT[r][s8 + 5] = b2.y; sT[r][s8 + 6] = b2.z; sT[r][s8 + 7] = b2.w;
  }
  __syncthreads();
  int nr = t >> 2, cs = (t & 3) * 16;
  int n2 = nr >> 1, nl = (nr & 1) * 16;
  unsigned pkv[8];
#pragma unroll
  for (int i = 0; i < 8; ++i) {
    unsigned lo = (sT[cs + 2 * i][n2] >> nl) & 0xFFFFu;
    unsigned hi = (sT[cs + 2 * i + 1][n2] >> nl) & 0xFFFFu;
    pkv[i] = lo | (hi << 16);
  }
  unsigned short* op = outT + ((size_t)b * NPOS + n0 + nr) * C + c0 + cs;
  *(uint4*)(op) = *(uint4*)&pkv[0];
  *(uint4*)(op + 8) = *(uint4*)&pkv[4];
}

// ---------------- MFMA pointwise qv GEMM: fqv_pw x dwtT -> fq, fv^T --------
__global__ __launch_bounds__(256) void k_pwqv_m(const unsigned short* __restrict__ dwtT,
                                                const float* __restrict__ pw,
                                                unsigned short* __restrict__ fqb,
                                                unsigned short* __restrict__ fvTb) {
  __shared__ __align__(16) char sAB[49152];  // sW [0,16K) | sB [16K,48K)
  char* sW = sAB;
  char* sB = sAB + 16384;
  int t = threadIdx.x, wave = t >> 6, lane = t & 63, g = lane >> 4, c = lane & 15;
  int n0 = blockIdx.x * 128, ti = blockIdx.y, b = blockIdx.z;
  int qv = ti >> 2, head = ti & 3, bh = b * 4 + head;

  {  // stage A: 64 dh x 128 k, permuted rows, swizzled, pitch 256B
    int r = t >> 2, ks = (t & 3) * 32;
    int co = qv * 256 + r * 4 + head;
    const float* wp = pw + (size_t)co * 128 + ks;
    unsigned pkv[16];
#pragma unroll
    for (int i = 0; i < 8; ++i) {
      float4 v = *(const float4*)(wp + i * 4);
      pkv[2 * i] = pk_bf16(v.x, v.y);
      pkv[2 * i + 1] = pk_bf16(v.z, v.w);
    }
#pragma unroll
    for (int u = 0; u < 4; ++u) {
      int colb = (ks * 2 + u * 16) ^ ((r & 7) << 4);
      *(uint4*)(sW + r * 256 + colb) = *(uint4*)&pkv[u * 4];
    }
  }
  const char* Bg = (const char*)(dwtT + ((size_t)b * NPOS + n0) * 128);
#pragma unroll
  for (int p = 0; p < 8; ++p) {  // stage B: 128 n x 128 k, pitch 256B
    int oo = p * 4096 + t * 16;
    int row = oo >> 8, col = (oo & 255) ^ (((oo >> 8) & 7) << 4);
    GL2LDS(Bg + (size_t)row * 256 + col, sB + oo);
  }
  __syncthreads();

  f32x4 acc[4][2];
#pragma unroll
  for (int ct = 0; ct < 4; ++ct)
#pragma unroll
    for (int jf = 0; jf < 2; ++jf) acc[ct][jf] = (f32x4){0.f, 0.f, 0.f, 0.f};
  int nw = wave * 32;
#pragma unroll
  for (int kc = 0; kc < 4; ++kc) {
    bf16x8 bq[2];
#pragma unroll
    for (int jf = 0; jf < 2; ++jf)
      bq[jf] = lds_fragP(sB, nw + jf * 16 + c, kc * 64 + g * 16, 256);
#pragma unroll
    for (int ct = 0; ct < 4; ++ct) {
      bf16x8 a = lds_fragP(sW, ct * 16 + c, kc * 64 + g * 16, 256);
#pragma unroll
      for (int jf = 0; jf < 2; ++jf)
        acc[ct][jf] = __builtin_amdgcn_mfma_f32_16x16x32_bf16(a, bq[jf], acc[ct][jf], 0, 0, 0);
    }
  }
  __syncthreads();

  // dump [n 128][dh 64] bf16, pitch 144B (bank-spread)
  char* dmp = sB;
#pragma unroll
  for (int ct = 0; ct < 4; ++ct)
#pragma unroll
    for (int jf = 0; jf < 2; ++jf) {
      int n = nw + jf * 16 + c;
      uint2 wv;
      wv.x = pk_bf16(acc[ct][jf][0], acc[ct][jf][1]);
      wv.y = pk_bf16(acc[ct][jf][2], acc[ct][jf][3]);
      *(uint2*)(dmp + n * 144 + (ct * 16 + 4 * g) * 2) = wv;
    }
  __syncthreads();

  if (qv == 0) {  // fq[bh][n][dh]: coalesced 64B row writes
    int nr = t >> 1, seg = t & 1;
    const char* src = dmp + nr * 144 + seg * 64;
    unsigned short* dst = fqb + ((size_t)bh * NPOS + n0 + nr) * 64 + seg * 32;
#pragma unroll
    for (int i = 0; i < 4; ++i)
      *(uint4*)(dst + i * 8) = *(const uint4*)(src + i * 16);
  } else {  // fvT[bh][dh][n]: transpose read from dump
#pragma unroll
    for (int it = 0; it < 2; ++it) {
      int idx = it * 256 + t;
      int dh = idx >> 3, nseg = (idx & 7) * 16;
      unsigned pkv[8];
#pragma unroll
      for (int i = 0; i < 8; ++i) {
        unsigned short lo = *(const unsigned short*)(dmp + (nseg + 2 * i) * 144 + dh * 2);
        unsigned short hi = *(const unsigned short*)(dmp + (nseg + 2 * i + 1) * 144 + dh * 2);
        pkv[i] = (unsigned)lo | ((unsigned)hi << 16);
      }
      unsigned short* dst = fvTb + ((size_t)bh * 64 + dh) * NPOS + n0 + nseg;
      *(uint4*)(dst) = *(uint4*)&pkv[0];
      *(uint4*)(dst + 8) = *(uint4*)&pkv[4];
    }
  }
}

// ---------------- MFMA pointwise out GEMM: fout_pw x dwoT -> out1 (fp32) ---
__global__ __launch_bounds__(256) void k_pwout_m(const unsigned short* __restrict__ dwoT,
                                                 const float* __restrict__ pw,
                                                 float* __restrict__ out1) {
  __shared__ __align__(16) char sW[32768];  // [64 co][512B k=256]
  __shared__ __align__(16) char sB[32768];  // [128 n][256B k-half]
  int t = threadIdx.x, wave = t >> 6, lane = t & 63, g = lane >> 4, c = lane & 15;
  int n0 = blockIdx.x * 128, ti = blockIdx.y, b = blockIdx.z;

  {  // stage A full k=256
    int r = t >> 2, ks = (t & 3) * 64;
    const float* wp = pw + (size_t)(ti * 64 + r) * 256 + ks;
    unsigned pkv[32];
#pragma unroll
    for (int i = 0; i < 16; ++i) {
      float4 v = *(const float4*)(wp + i * 4);
      pkv[2 * i] = pk_bf16(v.x, v.y);
      pkv[2 * i + 1] = pk_bf16(v.z, v.w);
    }
#pragma unroll
    for (int u = 0; u < 8; ++u) {
      int colb = (ks * 2 + u * 16) ^ ((r & 7) << 4);
      *(uint4*)(sW + r * 512 + colb) = *(uint4*)&pkv[u * 4];
    }
  }

  f32x4 acc[4][2];
#pragma unroll
  for (int ct = 0; ct < 4; ++ct)
#pragma unroll
    for (int jf = 0; jf < 2; ++jf) acc[ct][jf] = (f32x4){0.f, 0.f, 0.f, 0.f};
  int nw = wave * 32;
  const char* Bg = (const char*)(dwoT + ((size_t)b * NPOS + n0) * 256);

  for (int kh = 0; kh < 2; ++kh) {
#pragma unroll
    for (int p = 0; p < 8; ++p) {
      int oo = p * 4096 + t * 16;
      int row = oo >> 8, col = (oo & 255) ^ (((oo >> 8) & 7) << 4);
      GL2LDS(Bg + (size_t)row * 512 + kh * 256 + col, sB + oo);
    }
    __syncthreads();
#pragma unroll
    for (int kc = 0; kc < 4; ++kc) {
      bf16x8 bq[2];
#pragma unroll
      for (int jf = 0; jf < 2; ++jf)
        bq[jf] = lds_fragP(sB, nw + jf * 16 + c, kc * 64 + g * 16, 256);
#pragma unroll
      for (int ct = 0; ct < 4; ++ct) {
        bf16x8 a = lds_fragP(sW, ct * 16 + c, (kh * 4 + kc) * 64 + g * 16, 512);
#pragma unroll
        for (int jf = 0; jf < 2; ++jf)
          acc[ct][jf] = __builtin_amdgcn_mfma_f32_16x16x32_bf16(a, bq[jf], acc[ct][jf], 0, 0, 0);
      }
    }
    __syncthreads();
  }
#pragma unroll
  for (int ct = 0; ct < 4; ++ct)
#pragma unroll
    for (int jf = 0; jf < 2; ++jf) {
      int n = n0 + nw + jf * 16 + c;
#pragma unroll
      for (int r = 0; r < 4; ++r) {
        int co = ti * 64 + ct * 16 + 4 * g + r;
        out1[((size_t)b * 128 + co) * NPOS + n] = acc[ct][jf][r];
      }
    }
}

// ---------------- MFMA attention row pass (LDS-staged, double-buffered) ----
__global__ __launch_bounds__(256) void k_attn_row(const unsigned short* __restrict__ fqb,
                                                  const unsigned short* __restrict__ mapqb,
                                                  const unsigned short* __restrict__ mapvTb,
                                                  unsigned short* __restrict__ F) {
  __shared__ __align__(16) char sK[2][8192];
  __shared__ __align__(16) char sV[2][8192];
  __shared__ __align__(16) unsigned sP[4][2][16][36];
  __shared__ float sL[4][2][16];
  int t = threadIdx.x, wave = t >> 6, lane = t & 63, g = lane >> 4, c = lane & 15;
  int bh = blockIdx.y;
  int j0 = blockIdx.x * 128 + wave * 32;

  const char* Kg = (const char*)(mapqb + (size_t)bh * MPOS * 64);
  const char* Vg = (const char*)(mapvTb + (size_t)bh * 64 * MPOS);

  const unsigned short* fqp = fqb + ((size_t)bh * NPOS + j0 + c) * 64 + 8 * g;
  bf16x8 bq00 = *(const bf16x8*)(fqp);
  bf16x8 bq01 = *(const bf16x8*)(fqp + 32);
  bf16x8 bq10 = *(const bf16x8*)(fqp + 16 * 64);
  bf16x8 bq11 = *(const bf16x8*)(fqp + 16 * 64 + 32);

  f32x4 o[2][4];
#pragma unroll
  for (int jf = 0; jf < 2; ++jf)
#pragma unroll
    for (int dt = 0; dt < 4; ++dt) o[jf][dt] = (f32x4){0.f, 0.f, 0.f, 0.f};
  float ls0 = 0.f, ls1 = 0.f;

#pragma unroll
  for (int p = 0; p < 2; ++p) {
    int oo = p * 4096 + t * 16;
    int row = oo >> 7, col = (oo & 127) ^ (((oo >> 7) & 7) << 4);
    GL2LDS(Kg + (size_t)row * 128 + col, sK[0] + oo);
    GL2LDS(Vg + (size_t)row * 1024 + col, sV[0] + oo);
  }
  __syncthreads();

  for (int ic = 0; ic < 8; ++ic) {
    const char* Kt = sK[ic & 1];
    const char* Vt = sV[ic & 1];
    if (ic < 7) {
      int ibase = (ic + 1) * 64;
#pragma unroll
      for (int p = 0; p < 2; ++p) {
        int oo = p * 4096 + t * 16;
        int row = oo >> 7, col = (oo & 127) ^ (((oo >> 7) & 7) << 4);
        GL2LDS(Kg + (size_t)(ibase + row) * 128 + col, sK[(ic + 1) & 1] + oo);
        GL2LDS(Vg + (size_t)row * 1024 + ibase * 2 + col, sV[(ic + 1) & 1] + oo);
      }
    }
#pragma unroll
    for (int ti = 0; ti < 4; ++ti) {
      bf16x8 a0 = lds_frag(Kt, ti * 16 + c, 16 * g);
      bf16x8 a1 = lds_frag(Kt, ti * 16 + c, 64 + 16 * g);
      f32x4 s0 = {0.f, 0.f, 0.f, 0.f}, s1 = {0.f, 0.f, 0.f, 0.f};
      s0 = __builtin_amdgcn_mfma_f32_16x16x32_bf16(a0, bq00, s0, 0, 0, 0);
      s0 = __builtin_amdgcn_mfma_f32_16x16x32_bf16(a1, bq01, s0, 0, 0, 0);
      s1 = __builtin_amdgcn_mfma_f32_16x16x32_bf16(a0, bq10, s1, 0, 0, 0);
      s1 = __builtin_amdgcn_mfma_f32_16x16x32_bf16(a1, bq11, s1, 0, 0, 0);
      float p0 = __expf(s0[0]), p1 = __expf(s0[1]), p2 = __expf(s0[2]), p3 = __expf(s0[3]);
      ls0 += (p0 + p1) + (p2 + p3);
      sP[wave][0][c][ti * 8 + 2 * g] = pk_bf16(p0, p1);
      sP[wave][0][c][ti * 8 + 2 * g + 1] = pk_bf16(p2, p3);
      float q0 = __expf(s1[0]), q1 = __expf(s1[1]), q2 = __expf(s1[2]), q3 = __expf(s1[3]);
      ls1 += (q0 + q1) + (q2 + q3);
      sP[wave][1][c][ti * 8 + 2 * g] = pk_bf16(q0, q1);
      sP[wave][1][c][ti * 8 + 2 * g + 1] = pk_bf16(q2, q3);
    }
#pragma unroll
    for (int ks = 0; ks < 2; ++ks) {
      bf16x8 ap0 = *(const bf16x8*)&sP[wave][0][c][ks * 16 + 4 * g];
      bf16x8 ap1 = *(const bf16x8*)&sP[wave][1][c][ks * 16 + 4 * g];
#pragma unroll
      for (int dt = 0; dt < 4; ++dt) {
        bf16x8 bv = lds_frag(Vt, dt * 16 + c, ks * 64 + 16 * g);
        o[0][dt] = __builtin_amdgcn_mfma_f32_16x16x32_bf16(ap0, bv, o[0][dt], 0, 0, 0);
        o[1][dt] = __builtin_amdgcn_mfma_f32_16x16x32_bf16(ap1, bv, o[1][dt], 0, 0, 0);
      }
    }
    __syncthreads();
  }

  ls0 += __shfl_xor(ls0, 16); ls0 += __shfl_xor(ls0, 32);
  ls1 += __shfl_xor(ls1, 16); ls1 += __shfl_xor(ls1, 32);
  if (g == 0) { sL[wave][0][c] = 1.f / ls0; sL[wave][1][c] = 1.f / ls1; }
  int b = bh >> 2, head = bh & 3;
#pragma unroll
  for (int jf = 0; jf < 2; ++jf) {
    float rl0 = sL[wave][jf][4 * g + 0], rl1 = sL[wave][jf][4 * g + 1];
    float rl2 = sL[wave][jf][4 * g + 2], rl3 = sL[wave][jf][4 * g + 3];
#pragma unroll
    for (int dt = 0; dt < 4; ++dt) {
      uint2 wv;
      wv.x = pk_bf16(o[jf][dt][0] * rl0, o[jf][dt][1] * rl1);
      wv.y = pk_bf16(o[jf][dt][2] * rl2, o[jf][dt][3] * rl3);
      *(uint2*)(F + ((size_t)b * INNER + head * 64 + dt * 16 + c) * NPOS +
                j0 + jf * 16 + 4 * g) = wv;
    }
  }
}

// ---------------- MFMA attention col pass (LDS-staged, j-chunked) ----------
__global__ __launch_bounds__(256) void k_attn_col(const unsigned short* __restrict__ fqb,
                                                  const unsigned short* __restrict__ fvTb,
                                                  const unsigned short* __restrict__ mapqb,
                                                  float* __restrict__ Gc,
                                                  float* __restrict__ Gl) {
  __shared__ __align__(16) char sQ[2][8192];
  __shared__ __align__(16) char sV[2][8192];
  __shared__ __align__(16) unsigned sP[4][2][16][36];
  int t = threadIdx.x, wave = t >> 6, lane = t & 63, g = lane >> 4, c = lane & 15;
  int bh = blockIdx.y, chunk = blockIdx.z;
  int i0 = blockIdx.x * 128 + wave * 32;
  int jb = chunk * JCHUNK;

  const char* Qg = (const char*)(fqb + (size_t)bh * NPOS * 64);
  const char* Vg = (const char*)(fvTb + (size_t)bh * 64 * NPOS);

  const unsigned short* kp = mapqb + ((size_t)bh * MPOS + i0 + c) * 64 + 8 * g;
  bf16x8 bm00 = *(const bf16x8*)(kp);
  bf16x8 bm01 = *(const bf16x8*)(kp + 32);
  bf16x8 bm10 = *(const bf16x8*)(kp + 16 * 64);
  bf16x8 bm11 = *(const bf16x8*)(kp + 16 * 64 + 32);

  f32x4 o[2][4];
#pragma unroll
  for (int f = 0; f < 2; ++f)
#pragma unroll
    for (int dt = 0; dt < 4; ++dt) o[f][dt] = (f32x4){0.f, 0.f, 0.f, 0.f};
  float lc0 = 0.f, lc1 = 0.f;

#pragma unroll
  for (int p = 0; p < 2; ++p) {
    int oo = p * 4096 + t * 16;
    int row = oo >> 7, col = (oo & 127) ^ (((oo >> 7) & 7) << 4);
    GL2LDS(Qg + (size_t)(jb + row) * 128 + col, sQ[0] + oo);
    GL2LDS(Vg + (size_t)row * (NPOS * 2) + jb * 2 + col, sV[0] + oo);
  }
  __syncthreads();

  for (int jc = 0; jc < JCHUNK / 64; ++jc) {
    const char* Qt = sQ[jc & 1];
    const char* Vt = sV[jc & 1];
    if (jc < JCHUNK / 64 - 1) {
      int jbase = jb + (jc + 1) * 64;
#pragma unroll
      for (int p = 0; p < 2; ++p) {
        int oo = p * 4096 + t * 16;
        int row = oo >> 7, col = (oo & 127) ^ (((oo >> 7) & 7) << 4);
        GL2LDS(Qg + (size_t)(jbase + row) * 128 + col, sQ[(jc + 1) & 1] + oo);
        GL2LDS(Vg + (size_t)row * (NPOS * 2) + jbase * 2 + col, sV[(jc + 1) & 1] + oo);
      }
    }
#pragma unroll
    for (int tj = 0; tj < 4; ++tj) {
      bf16x8 a0 = lds_frag(Qt, tj * 16 + c, 16 * g);
      bf16x8 a1 = lds_frag(Qt, tj * 16 + c, 64 + 16 * g);
      f32x4 s0 = {0.f, 0.f, 0.f, 0.f}, s1 = {0.f, 0.f, 0.f, 0.f};
      s0 = __builtin_amdgcn_mfma_f32_16x16x32_bf16(a0, bm00, s0, 0, 0, 0);
      s0 = __builtin_amdgcn_mfma_f32_16x16x32_bf16(a1, bm01, s0, 0, 0, 0);
      s1 = __builtin_amdgcn_mfma_f32_16x16x32_bf16(a0, bm10, s1, 0, 0, 0);
      s1 = __builtin_amdgcn_mfma_f32_16x16x32_bf16(a1, bm11, s1, 0, 0, 0);
      float p0 = __expf(s0[0]), p1 = __expf(s0[1]), p2 = __expf(s0[2]), p3 = __expf(s0[3]);
      lc0 += (p0 + p1) + (p2 + p3);
      sP[wave][0][c][tj * 8 + 2 * g] = pk_bf16(p0, p1);
      sP[wave][0][c][tj * 8 + 2 * g + 1] = pk_bf16(p2, p3);
      float q0 = __expf(s1[0]), q1 = __expf(s1[1]), q2 = __expf(s1[2]), q3 = __expf(s1[3]);
      lc1 += (q0 + q1) + (q2 + q3);
      sP[wave][1][c][tj * 8 + 2 * g] = pk_bf16(q0, q1);
      sP[wave][1][c][tj * 8 + 2 * g + 1] = pk_bf16(q2, q3);
    }
#pragma unroll
    for (int ks = 0; ks < 2; ++ks) {
      bf16x8 ap0 = *(const bf16x8*)&sP[wave][0][c][ks * 16 + 4 * g];
      bf16x8 ap1 = *(const bf16x8*)&sP[wave][1][c][ks * 16 + 4 * g];
#pragma unroll
      for (int dt = 0; dt < 4; ++dt) {
        bf16x8 bv = lds_frag(Vt, dt * 16 + c, ks * 64 + 16 * g);
        o[0][dt] = __builtin_amdgcn_mfma_f32_16x16x32_bf16(ap0, bv, o[0][dt], 0, 0, 0);
        o[1][dt] = __builtin_amdgcn_mfma_f32_16x16x32_bf16(ap1, bv, o[1][dt], 0, 0, 0);
      }
    }
    __syncthreads();
  }

  lc0 += __shfl_xor(lc0, 16); lc0 += __shfl_xor(lc0, 32);
  lc1 += __shfl_xor(lc1, 16); lc1 += __shfl_xor(lc1, 32);
  int gi = chunk * 8 + bh;
  if (g == 0) {
    Gl[(size_t)gi * MPOS + i0 + c] = lc0;
    Gl[(size_t)gi * MPOS + i0 + 16 + c] = lc1;
  }
  float* gp = Gc + ((size_t)gi * MPOS + i0) * 64;
#pragma unroll
  for (int f = 0; f < 2; ++f)
#pragma unroll
    for (int dt = 0; dt < 4; ++dt)
#pragma unroll
      for (int r = 0; r < 4; ++r)
        gp[(size_t)(f * 16 + 4 * g + r) * 64 + dt * 16 + c] = o[f][dt][r];
}

// ---------------- combine col partials + map_out projection ----------------
__global__ __launch_bounds__(256) void k_map_out(const float* __restrict__ Gc,
                                                 const float* __restrict__ Gl,
                                                 const float* __restrict__ mow,
                                                 float* __restrict__ out2) {
  int m = blockIdx.x, b = blockIdx.y, t = threadIdx.x;
  __shared__ float sMA[256];
  __shared__ float sL[4];
  if (t < 4) {
    float l = 0.f;
#pragma unroll 4
    for (int ch = 0; ch < JSPLIT; ++ch) l += Gl[(size_t)(ch * 8 + b * 4 + t) * MPOS + m];
    sL[t] = 1.f / l;
  }
  __syncthreads();
  {
    int head = t & 3, dh = t >> 2;
    int bh = b * 4 + head;
    float a = 0.f;
#pragma unroll 4
    for (int ch = 0; ch < JSPLIT; ++ch)
      a += Gc[((size_t)(ch * 8 + bh) * MPOS + m) * 64 + dh];
    sMA[t] = a * sL[head];
  }
  __syncthreads();
  if (t < 64) {
    const float* wr = mow + t * 256;
    float acc = 0.f;
#pragma unroll 4
    for (int c = 0; c < 256; ++c) acc += wr[c] * sMA[c];
    out2[((size_t)b * 64 + t) * MPOS + m] = acc;
  }
}

extern "C" void kernel_launch(void* const* d_in, const int* in_sizes, int n_in,
                              void* d_out, int out_size, void* d_ws, size_t ws_size,
                              hipStream_t stream) {
  const float* feat = (const float*)d_in[0];
  const float* smap = (const float*)d_in[1];
  const float* fqv_dw = (const float*)d_in[2];
  const float* fqv_pw = (const float*)d_in[3];
  const float* fout_dw = (const float*)d_in[4];
  const float* fout_pw = (const float*)d_in[5];
  const float* mqv_w = (const float*)d_in[6];
  const float* mout_w = (const float*)d_in[7];

  float* out = (float*)d_out;
  float* out1 = out;                              // [2,128,24,24,24]
  float* out2 = out + (size_t)BB * 128 * NPOS;    // [2,64,8,8,8]

  const size_t QV = (size_t)BB * HEADS * NPOS * DH;   // 7,077,888
  const size_t MQV = (size_t)BB * HEADS * MPOS * DH;  // 262,144
  float* ws = (float*)d_ws;
  unsigned short* F = (unsigned short*)ws;             // bf16 attn row output (region QV floats)
  unsigned short* fqb = (unsigned short*)(ws + QV);    // bf16 [bh][j][d]
  unsigned short* fvTb = fqb + QV;                     // bf16 [bh][d][j]
  unsigned short* mapqb = fvTb + QV;                   // bf16 [bh][i][d] (scaled)
  unsigned short* mapvTb = mapqb + MQV;                // bf16 [bh][d][i]
  float* Gc = (float*)(mapvTb + MQV);                  // [JSPLIT*8][512][64]
  float* Gl = Gc + (size_t)JSPLIT * 8 * MPOS * 64;     // [JSPLIT*8][512]

  // lifetime-disjoint aliases
  unsigned short* dwt = (unsigned short*)out1;  // dw1 out bf16 [b][128][N]; dead after tr1
  unsigned short* dwtT = (unsigned short*)Gc;   // [b][N][128] bf16; dead before attn_col
  unsigned short* dwt2 = fqb;                   // dw2 out bf16 [b][256][N]; fq dead after attn_col
  unsigned short* dwoT = (unsigned short*)ws;   // [b][N][256] bf16; F dead after dw2

  k_map_qv<<<dim3(BB * MPOS), dim3(512), 0, stream>>>(smap, mqv_w, mapqb, mapvTb);
  k_dw_f2b<<<dim3(BB * CH_FEAT), dim3(576), 0, stream>>>(feat, fqv_dw, dwt, CH_FEAT);
  k_trb<<<dim3(NPOS / 64, CH_FEAT / 64, BB), dim3(256), 0, stream>>>(dwt, dwtT, CH_FEAT);
  k_pwqv_m<<<dim3(NPOS / 128, 8, BB), dim3(256), 0, stream>>>(dwtT, fqv_pw, fqb, fvTb);
  k_attn_row<<<dim3(NPOS / 128, BB * HEADS), dim3(256), 0, stream>>>(fqb, mapqb, mapvTb, F);
  k_attn_col<<<dim3(MPOS / 128, BB * HEADS, JSPLIT), dim3(256), 0, stream>>>(fqb, fvTb, mapqb, Gc, Gl);
  k_map_out<<<dim3(MPOS, BB), dim3(256), 0, stream>>>(Gc, Gl, mout_w, out2);
  k_dw_b2b<<<dim3(BB * INNER), dim3(576), 0, stream>>>(F, fout_dw, dwt2, INNER);
  k_trb<<<dim3(NPOS / 64, INNER / 64, BB), dim3(256), 0, stream>>>(dwt2, dwoT, INNER);
  k_pwout_m<<<dim3(NPOS / 128, 2, BB), dim3(256), 0, stream>>>(dwoT, fout_pw, out1);
}